// Round 8
// baseline (817.416 us; speedup 1.0000x reference)
//
#include <hip/hip_runtime.h>

#define N2 2048      // B*P
#define N8 8192      // B*P*UP
#define CDIM 384
#define H1C 192      // C/2
#define H2C 96       // C/4
#define PDIM 512
#define KRR 16
#define FOLDH 256
#define XCAP 256
#define XTILE 1024
#define INFF 3.0e38f

__device__ __forceinline__ float frelu(float x) { return x > 0.f ? x : 0.f; }

// ---------------- 64-lane bitonic sorts (ascending) --------------------------------
__device__ __forceinline__ void bitonic64_val(float& d, int lane) {
    #pragma unroll
    for (int k = 2; k <= 64; k <<= 1) {
        #pragma unroll
        for (int j = k >> 1; j > 0; j >>= 1) {
            float od = __shfl_xor(d, j);
            bool lower = (lane & j) == 0;
            bool olt = od < d;
            bool take = lower ? olt : !olt;
            if (lane & k) take = !take;
            if (take) d = od;
        }
    }
}

__device__ __forceinline__ void bitonic64_pair(float& d, int& c, int lane) {
    #pragma unroll
    for (int k = 2; k <= 64; k <<= 1) {
        #pragma unroll
        for (int j = k >> 1; j > 0; j >>= 1) {
            float od = __shfl_xor(d, j);
            int   oc = __shfl_xor(c, j);
            bool lower = (lane & j) == 0;
            bool olt = (od < d) || (od == d && oc < c);
            bool take = lower ? olt : !olt;
            if (lane & k) take = !take;
            if (take) { d = od; c = oc; }
        }
    }
}

// ---------------- slow exact select fallback (cnt > 64, rare) ----------------------
__device__ __forceinline__ void select_slow(const float* bd, const int* bi, int cnt,
                                            int ksel, int row, int n, int* out, int lane) {
    float cd[4]; int cix[4];
    #pragma unroll
    for (int s = 0; s < 4; ++s) {
        int c = lane + 64*s;
        bool v = c < cnt;
        cd[s]  = v ? bd[c] : INFF;
        cix[s] = v ? bi[c] : 0x7fffffff;
    }
    for (int r = 0; r < ksel; ++r) {
        float lv = cd[0]; int li = cix[0];
        #pragma unroll
        for (int s = 1; s < 4; ++s) {
            if (cd[s] < lv || (cd[s] == lv && cix[s] < li)) { lv = cd[s]; li = cix[s]; }
        }
        float wv = lv; int wi = li;
        #pragma unroll
        for (int s = 1; s < 64; s <<= 1) {
            float ov = __shfl_xor(wv, s); int oi = __shfl_xor(wi, s);
            if (ov < wv || (ov == wv && oi < wi)) { wv = ov; wi = oi; }
        }
        if (lane == 0) {
            int safe = ((unsigned)wi < (unsigned)n) ? wi : ((row + 1) & (n - 1));
            out[row*ksel + r] = safe;
        }
        #pragma unroll
        for (int s = 0; s < 4; ++s) {
            if (cd[s] == wv && cix[s] == wi) { cd[s] = INFF; cix[s] = 0x7fffffff; }
        }
    }
}

// ---------------- row squared norms (wave per row) ---------------------------------
__global__ __launch_bounds__(256) void rowsq_kernel(const float* __restrict__ x,
                                                    float* __restrict__ sq, int d) {
    int wave = threadIdx.x >> 6, lane = threadIdx.x & 63;
    int row = blockIdx.x*4 + wave;
    float acc = 0.f;
    for (int k = lane; k < d; k += 64) { float v = x[(size_t)row*d + k]; acc += v*v; }
    #pragma unroll
    for (int s = 1; s < 64; s <<= 1) acc += __shfl_xor(acc, s);
    if (lane == 0) sq[row] = acc;
}

// ---------------- weight transposes (c1w2 192x192, c2w2 96x96) ---------------------
__global__ __launch_bounds__(256) void wtrans_kernel(const float* __restrict__ w1, float* __restrict__ o1,
                                                     const float* __restrict__ w2, float* __restrict__ o2) {
    int i = blockIdx.x*256 + threadIdx.x;
    if (blockIdx.y == 0) {
        if (i < 192*192) { int h = i / 192, c = i - h*192; o1[c*192 + h] = w1[i]; }
    } else {
        if (i < 96*96) { int h = i / 96, c = i - h*96; o2[c*96 + h] = w2[i]; }
    }
}

// ---------------- triangular symmetric dist: direct + mirrored tile ----------------
__device__ __forceinline__ void disttri_body(const float* __restrict__ x, const float* __restrict__ sq,
                                             float* __restrict__ dist, int n, int K) {
    int l = blockIdx.x;
    int by = (int)((sqrtf(8.f*(float)l + 1.f) - 1.f)*0.5f);
    while ((by+1)*(by+2)/2 <= l) ++by;
    while (by*(by+1)/2 > l) --by;
    int bx = l - by*(by+1)/2;
    int row0 = by*64, col0 = bx*64;
    __shared__ __align__(16) float As[16][68];
    __shared__ __align__(16) float Bs[16][68];
    __shared__ __align__(16) float T[64][68];
    int tx = threadIdx.x, ty = threadIdx.y;
    int t = ty*16 + tx;
    float acc[4][4] = {};
    for (int k0 = 0; k0 < K; k0 += 16) {
        #pragma unroll
        for (int r = 0; r < 4; ++r) {
            int e = t + 256*r; int kk = e & 15, mm = e >> 4;
            As[kk][mm] = x[(size_t)(row0+mm)*K + k0+kk];
            Bs[kk][mm] = x[(size_t)(col0+mm)*K + k0+kk];
        }
        __syncthreads();
        #pragma unroll
        for (int kk = 0; kk < 16; ++kk) {
            float4 a4 = *(const float4*)&As[kk][ty*4];
            float4 b4 = *(const float4*)&Bs[kk][tx*4];
            acc[0][0] += a4.x*b4.x; acc[0][1] += a4.x*b4.y; acc[0][2] += a4.x*b4.z; acc[0][3] += a4.x*b4.w;
            acc[1][0] += a4.y*b4.x; acc[1][1] += a4.y*b4.y; acc[1][2] += a4.y*b4.z; acc[1][3] += a4.y*b4.w;
            acc[2][0] += a4.z*b4.x; acc[2][1] += a4.z*b4.y; acc[2][2] += a4.z*b4.z; acc[2][3] += a4.z*b4.w;
            acc[3][0] += a4.w*b4.x; acc[3][1] += a4.w*b4.y; acc[3][2] += a4.w*b4.z; acc[3][3] += a4.w*b4.w;
        }
        __syncthreads();
    }
    bool mirror = (row0 != col0);
    #pragma unroll
    for (int i2 = 0; i2 < 4; ++i2) {
        int row = row0 + ty*4 + i2;
        float sr = sq[row];
        float4 o;
        o.x = sr + sq[col0+tx*4+0] - 2.f*acc[i2][0];
        o.y = sr + sq[col0+tx*4+1] - 2.f*acc[i2][1];
        o.z = sr + sq[col0+tx*4+2] - 2.f*acc[i2][2];
        o.w = sr + sq[col0+tx*4+3] - 2.f*acc[i2][3];
        *(float4*)&dist[(size_t)row*n + col0 + tx*4] = o;
        if (mirror) {
            T[tx*4+0][ty*4+i2] = o.x;
            T[tx*4+1][ty*4+i2] = o.y;
            T[tx*4+2][ty*4+i2] = o.z;
            T[tx*4+3][ty*4+i2] = o.w;
        }
    }
    if (mirror) {
        __syncthreads();
        #pragma unroll
        for (int i2 = 0; i2 < 4; ++i2) {
            int orow = col0 + ty*4 + i2;
            float4 o = *(const float4*)&T[ty*4+i2][tx*4];
            *(float4*)&dist[(size_t)orow*n + row0 + tx*4] = o;
        }
    }
}

__global__ __launch_bounds__(256) void dist64tri_kernel(const float* __restrict__ x,
                                                        const float* __restrict__ sq,
                                                        float* __restrict__ dist, int n, int K) {
    disttri_body(x, sq, dist, n, K);
}

__global__ __launch_bounds__(256) void distpairtri_kernel(const float* __restrict__ xA,
                                                          const float* __restrict__ sqA,
                                                          float* __restrict__ dA,
                                                          const float* __restrict__ xB,
                                                          const float* __restrict__ sqB,
                                                          float* __restrict__ dB, int n, int K) {
    const float* x  = blockIdx.z ? xB : xA;
    const float* sq = blockIdx.z ? sqB : sqA;
    float* dist     = blockIdx.z ? dB : dA;
    disttri_body(x, sq, dist, n, K);
}

// ---------------- shared 64x64 GEMM tile body: C = A @ (Bw - BwB) + bias -----------
__device__ __forceinline__ void gemm_body(const float* __restrict__ A, const float* __restrict__ Bw,
                                          const float* __restrict__ BwB, const float* __restrict__ bias,
                                          float* __restrict__ C, int m, int K) {
    __shared__ __align__(16) float As[16][68];
    __shared__ __align__(16) float Bs[16][68];
    int tx = threadIdx.x, ty = threadIdx.y;
    int t = ty*16 + tx;
    int row0 = blockIdx.y*64, col0 = blockIdx.x*64;
    float acc[4][4] = {};
    for (int k0 = 0; k0 < K; k0 += 16) {
        #pragma unroll
        for (int r = 0; r < 4; ++r) {
            int e = t + 256*r; int kk = e & 15, mm = e >> 4;
            As[kk][mm] = (k0 + kk < K) ? A[(size_t)(row0+mm)*K + k0+kk] : 0.f;
        }
        #pragma unroll
        for (int r = 0; r < 4; ++r) {
            int e = t + 256*r; int nn = e & 63, kk = e >> 6;
            int col = col0 + nn, k = k0 + kk;
            float bv = 0.f;
            if (k < K && col < m) {
                bv = Bw[(size_t)k*m + col];
                if (BwB) bv -= BwB[(size_t)k*m + col];
            }
            Bs[kk][nn] = bv;
        }
        __syncthreads();
        #pragma unroll
        for (int kk = 0; kk < 16; ++kk) {
            float4 a4 = *(const float4*)&As[kk][ty*4];
            float4 b4 = *(const float4*)&Bs[kk][tx*4];
            acc[0][0] += a4.x*b4.x; acc[0][1] += a4.x*b4.y; acc[0][2] += a4.x*b4.z; acc[0][3] += a4.x*b4.w;
            acc[1][0] += a4.y*b4.x; acc[1][1] += a4.y*b4.y; acc[1][2] += a4.y*b4.z; acc[1][3] += a4.y*b4.w;
            acc[2][0] += a4.z*b4.x; acc[2][1] += a4.z*b4.y; acc[2][2] += a4.z*b4.z; acc[2][3] += a4.z*b4.w;
            acc[3][0] += a4.w*b4.x; acc[3][1] += a4.w*b4.y; acc[3][2] += a4.w*b4.z; acc[3][3] += a4.w*b4.w;
        }
        __syncthreads();
    }
    #pragma unroll
    for (int i2 = 0; i2 < 4; ++i2) {
        int row = row0 + ty*4 + i2;
        #pragma unroll
        for (int j2 = 0; j2 < 4; ++j2) {
            int col = col0 + tx*4 + j2;
            if (col < m) C[(size_t)row*m + col] = acc[i2][j2] + (bias ? bias[col] : 0.f);
        }
    }
}

__global__ __launch_bounds__(256) void gemmquad_kernel(
    const float* A0, const float* Bw0, const float* BwB0, const float* bias0, float* C0,
    const float* A1, const float* Bw1, const float* BwB1, const float* bias1, float* C1,
    const float* A2, const float* Bw2, const float* BwB2, const float* bias2, float* C2,
    const float* A3, const float* Bw3, const float* BwB3, const float* bias3, float* C3,
    int m, int K) {
    int z = blockIdx.z;
    const float* A    = (z==0)?A0 :(z==1)?A1 :(z==2)?A2 :A3;
    const float* Bw   = (z==0)?Bw0:(z==1)?Bw1:(z==2)?Bw2:Bw3;
    const float* BwB  = (z==0)?BwB0:(z==1)?BwB1:(z==2)?BwB2:BwB3;
    const float* bias = (z==0)?bias0:(z==1)?bias1:(z==2)?bias2:bias3;
    float* C          = (z==0)?C0 :(z==1)?C1 :(z==2)?C2 :C3;
    gemm_body(A, Bw, BwB, bias, C, m, K);
}

// refiner gather-GEMM pair: A row gathered from [featd(96) | xyzg(3)], K = 99
__global__ __launch_bounds__(256) void gatherpair_kernel(
    const float* __restrict__ featd, const float* __restrict__ xyzg,
    const float* Bw0, const float* BwB0, const float* bias0, float* C0,
    const float* Bw1, const float* BwB1, const float* bias1, float* C1,
    int m, int K) {
    int z = blockIdx.z;
    const float* Bw   = z ? Bw1 : Bw0;
    const float* BwB  = z ? BwB1 : BwB0;
    const float* bias = z ? bias1 : bias0;
    float* C          = z ? C1 : C0;
    __shared__ __align__(16) float As[16][68];
    __shared__ __align__(16) float Bs[16][68];
    int tx = threadIdx.x, ty = threadIdx.y;
    int t = ty*16 + tx;
    int row0 = blockIdx.y*64, col0 = blockIdx.x*64;
    float acc[4][4] = {};
    for (int k0 = 0; k0 < K; k0 += 16) {
        #pragma unroll
        for (int r = 0; r < 4; ++r) {
            int e = t + 256*r; int kk = e & 15, mm = e >> 4;
            int k = k0 + kk, grow = row0 + mm;
            float av = 0.f;
            if (k < K) {
                if (k < 96) { int b = grow >> 11, p = (grow & 2047) >> 2;
                              av = featd[(size_t)(b*PDIM + p)*H2C + k]; }
                else av = xyzg[(size_t)grow*3 + (k - 96)];
            }
            As[kk][mm] = av;
        }
        #pragma unroll
        for (int r = 0; r < 4; ++r) {
            int e = t + 256*r; int nn = e & 63, kk = e >> 6;
            int col = col0 + nn, k = k0 + kk;
            float bv = 0.f;
            if (k < K && col < m) {
                bv = Bw[(size_t)k*m + col];
                if (BwB) bv -= BwB[(size_t)k*m + col];
            }
            Bs[kk][nn] = bv;
        }
        __syncthreads();
        #pragma unroll
        for (int kk = 0; kk < 16; ++kk) {
            float4 a4 = *(const float4*)&As[kk][ty*4];
            float4 b4 = *(const float4*)&Bs[kk][tx*4];
            acc[0][0] += a4.x*b4.x; acc[0][1] += a4.x*b4.y; acc[0][2] += a4.x*b4.z; acc[0][3] += a4.x*b4.w;
            acc[1][0] += a4.y*b4.x; acc[1][1] += a4.y*b4.y; acc[1][2] += a4.y*b4.z; acc[1][3] += a4.y*b4.w;
            acc[2][0] += a4.z*b4.x; acc[2][1] += a4.z*b4.y; acc[2][2] += a4.z*b4.z; acc[2][3] += a4.z*b4.w;
            acc[3][0] += a4.w*b4.x; acc[3][1] += a4.w*b4.y; acc[3][2] += a4.w*b4.z; acc[3][3] += a4.w*b4.w;
        }
        __syncthreads();
    }
    #pragma unroll
    for (int i2 = 0; i2 < 4; ++i2) {
        int row = row0 + ty*4 + i2;
        #pragma unroll
        for (int j2 = 0; j2 < 4; ++j2) {
            int col = col0 + tx*4 + j2;
            if (col < m) C[(size_t)row*m + col] = acc[i2][j2] + (bias ? bias[col] : 0.f);
        }
    }
}

// ---------------- knn from dist rows (4 rows/block, bitonic select) ----------------
__global__ __launch_bounds__(256) void knn_dist_rt_kernel(const float* __restrict__ dA,
                                                          const float* __restrict__ dB, int n,
                                                          int* __restrict__ outA, int* __restrict__ outB,
                                                          int kA, int kB, int nblkA) {
    int wave = threadIdx.x >> 6, lane = threadIdx.x & 63;
    bool useB = (int)blockIdx.x >= nblkA;
    const float* dist = useB ? dB : dA;
    int* out = useB ? outB : outA;
    int ksel = useB ? kB : kA;
    int bx = useB ? (int)blockIdx.x - nblkA : (int)blockIdx.x;
    int row = bx*4 + wave;
    __shared__ float bufd[4][XCAP];
    __shared__ int   bufi[4][XCAP];
    __shared__ int   lcnt[4];
    const float4* drow = (const float4*)(dist + (size_t)row*n);
    int nq = n >> 2;
    float mv = INFF;
    for (int i = lane; i < nq; i += 64) {
        float4 d4 = drow[i]; int base = i*4;
        float a = (base+0 == row) ? INFF : d4.x;
        float b = (base+1 == row) ? INFF : d4.y;
        float c = (base+2 == row) ? INFF : d4.z;
        float d = (base+3 == row) ? INFF : d4.w;
        mv = fminf(mv, fminf(fminf(a,b), fminf(c,d)));
    }
    float sd = mv;
    bitonic64_val(sd, lane);
    float Tv = __shfl(sd, ksel - 1);
    if (lane == 0) lcnt[wave] = 0;
    for (int i = lane; i < nq; i += 64) {
        float4 d4 = drow[i]; int base = i*4;
        float dv4[4] = {d4.x, d4.y, d4.z, d4.w};
        #pragma unroll
        for (int q = 0; q < 4; ++q) {
            int col = base + q;
            if (col != row && dv4[q] <= Tv) {
                int pos = atomicAdd(&lcnt[wave], 1);
                if (pos < XCAP) { bufd[wave][pos] = dv4[q]; bufi[wave][pos] = col; }
            }
        }
    }
    int cnt = lcnt[wave]; if (cnt > XCAP) cnt = XCAP;
    if (cnt <= 64) {
        float d = (lane < cnt) ? bufd[wave][lane] : INFF;
        int   c = (lane < cnt) ? bufi[wave][lane] : 0x7fffffff;
        bitonic64_pair(d, c, lane);
        if (lane < ksel) {
            int safe = ((unsigned)c < (unsigned)n) ? c : ((row + 1) & (n - 1));
            out[row*ksel + lane] = safe;
        }
    } else {
        select_slow(bufd[wave], bufi[wave], cnt, ksel, row, n, out, lane);
    }
}

// ---------------- knn over packed xyz: 8 rows/block, 2 rows/wave -------------------
__global__ __launch_bounds__(256) void knn_xyz8_kernel(const float4* __restrict__ pts, int n,
                                                       int* __restrict__ out_idx) {
    int tid = threadIdx.x, wave = tid >> 6, lane = tid & 63;
    int rbase = blockIdx.x*8 + wave*2;
    __shared__ __align__(16) float4 tile[XTILE];
    __shared__ float bufd[8][XCAP];
    __shared__ int   bufi[8][XCAP];
    __shared__ int   lcnt[8];
    float4 P0 = pts[rbase], P1 = pts[rbase + 1];
    float mv0 = INFF, mv1 = INFF;
    for (int t0 = 0; t0 < n; t0 += XTILE) {
        __syncthreads();
        #pragma unroll
        for (int k = 0; k < XTILE/256; ++k) tile[tid + 256*k] = pts[t0 + tid + 256*k];
        __syncthreads();
        for (int c = lane; c < XTILE; c += 64) {
            float4 q = tile[c];
            int col = t0 + c;
            float d0 = P0.w + q.w - 2.f*(P0.x*q.x + P0.y*q.y + P0.z*q.z);
            float d1 = P1.w + q.w - 2.f*(P1.x*q.x + P1.y*q.y + P1.z*q.z);
            d0 = (col == rbase)     ? INFF : d0;
            d1 = (col == rbase + 1) ? INFF : d1;
            mv0 = fminf(mv0, d0);
            mv1 = fminf(mv1, d1);
        }
    }
    float s0 = mv0, s1 = mv1;
    bitonic64_val(s0, lane);
    bitonic64_val(s1, lane);
    float Tv0 = __shfl(s0, 15);
    float Tv1 = __shfl(s1, 15);
    if (lane < 2) lcnt[wave*2 + lane] = 0;
    for (int t0 = 0; t0 < n; t0 += XTILE) {
        __syncthreads();
        #pragma unroll
        for (int k = 0; k < XTILE/256; ++k) tile[tid + 256*k] = pts[t0 + tid + 256*k];
        __syncthreads();
        for (int c = lane; c < XTILE; c += 64) {
            float4 q = tile[c];
            int col = t0 + c;
            float d0 = P0.w + q.w - 2.f*(P0.x*q.x + P0.y*q.y + P0.z*q.z);
            float d1 = P1.w + q.w - 2.f*(P1.x*q.x + P1.y*q.y + P1.z*q.z);
            if (col != rbase && d0 <= Tv0) {
                int pos = atomicAdd(&lcnt[wave*2], 1);
                if (pos < XCAP) { bufd[wave*2][pos] = d0; bufi[wave*2][pos] = col; }
            }
            if (col != rbase + 1 && d1 <= Tv1) {
                int pos = atomicAdd(&lcnt[wave*2 + 1], 1);
                if (pos < XCAP) { bufd[wave*2 + 1][pos] = d1; bufi[wave*2 + 1][pos] = col; }
            }
        }
    }
    for (int jj = 0; jj < 2; ++jj) {
        int brow = wave*2 + jj, row = rbase + jj;
        int cnt = lcnt[brow]; if (cnt > XCAP) cnt = XCAP;
        if (cnt <= 64) {
            float d = (lane < cnt) ? bufd[brow][lane] : INFF;
            int   c = (lane < cnt) ? bufi[brow][lane] : 0x7fffffff;
            bitonic64_pair(d, c, lane);
            if (lane < 16) {
                int safe = ((unsigned)c < (unsigned)n) ? c : ((row + 1) & (n - 1));
                out_idx[row*16 + lane] = safe;
            }
        } else {
            select_slow(bufd[brow], bufi[brow], cnt, 16, row, n, out_idx, lane);
        }
    }
}

// ---------------- EdgeConv body: col-chunked acc (no spill), transposed w2 ---------
template<int H1, int H2, int KN, int SELF>
__device__ __forceinline__ void edge_body(float* st, float* sf_, float* st2_,
                                          const float* __restrict__ u, const float* __restrict__ v,
                                          const float* __restrict__ w2t, const float* __restrict__ b2,
                                          const int* __restrict__ idx, int idxs,
                                          float* __restrict__ out, float* __restrict__ out_sq,
                                          const float* __restrict__ cdw1, const float* __restrict__ cdb1,
                                          const float* __restrict__ cdw2, const float* __restrict__ cdb2,
                                          const float* __restrict__ ctx_xyz, float* __restrict__ out_xyz,
                                          int npts) {
    constexpr int E  = KN + SELF;
    constexpr int NT = (H1 + 63) / 64;
    constexpr int NC = (H2 + 63) / 64;
    int i = blockIdx.x;
    int lane = threadIdx.x; // 64 threads
    float suh[NT];
    #pragma unroll
    for (int t = 0; t < NT; ++t) {
        int h = lane + 64*t;
        suh[t] = (h < H1) ? u[(size_t)i*H1 + h] : 0.f;
    }
    #pragma unroll
    for (int e = 0; e < E; ++e) {
        int j = (SELF && e == 0) ? i : idx[i*idxs + (e - SELF)];
        j = ((unsigned)j < (unsigned)npts) ? j : i;
        #pragma unroll
        for (int t = 0; t < NT; ++t) {
            int h = lane + 64*t;
            if (h < H1) st[e*H1 + h] = frelu(suh[t] + v[(size_t)j*H1 + h]);
        }
    }
    __syncthreads();
    float vals[NC];
    // column-chunk: only acc[E] live at a time -> no scratch spill (was acc[E][NC])
    #pragma unroll
    for (int cc = 0; cc < NC; ++cc) {
        int col = lane + 64*cc;
        float acc[E];
        #pragma unroll
        for (int e = 0; e < E; ++e) acc[e] = 0.f;
        for (int h0 = 0; h0 < H1; h0 += 4) {
            float4 w4 = (col < H2) ? *(const float4*)&w2t[(size_t)col*H1 + h0]
                                   : make_float4(0.f, 0.f, 0.f, 0.f);
            #pragma unroll
            for (int e = 0; e < E; ++e) {
                float4 s4 = *(const float4*)&st[e*H1 + h0];
                acc[e] += s4.x*w4.x + s4.y*w4.y + s4.z*w4.z + s4.w*w4.w;
            }
        }
        if (col < H2) {
            float best = acc[0];
            #pragma unroll
            for (int e = 1; e < E; ++e) best = fmaxf(best, acc[e]);
            vals[cc] = best + b2[col];
            if (out) out[(size_t)i*H2 + col] = vals[cc];
        } else vals[cc] = 0.f;
    }
    if (out_sq) {
        float part = 0.f;
        #pragma unroll
        for (int c = 0; c < NC; ++c) part += vals[c]*vals[c];
        #pragma unroll
        for (int s = 1; s < 64; s <<= 1) part += __shfl_xor(part, s);
        if (lane == 0) out_sq[i] = part;
    }
    if (H2 == 96 && cdw1) {
        #pragma unroll
        for (int c = 0; c < NC; ++c) {
            int col = lane + 64*c;
            if (col < 96) sf_[col] = vals[c];
        }
        __syncthreads();
        #pragma unroll
        for (int c = 0; c < 2; ++c) {
            int col = lane + 64*c;
            if (col < 96) {
                float a = cdb1[col];
                for (int k = 0; k < 96; ++k) a += sf_[k]*cdw1[k*96 + col];
                st2_[col] = frelu(a);
            }
        }
        __syncthreads();
        float s0 = st2_[lane];
        float p0 = s0*cdw2[lane*3+0], p1 = s0*cdw2[lane*3+1], p2 = s0*cdw2[lane*3+2];
        if (lane < 32) {
            float s1 = st2_[lane+64];
            p0 += s1*cdw2[(lane+64)*3+0];
            p1 += s1*cdw2[(lane+64)*3+1];
            p2 += s1*cdw2[(lane+64)*3+2];
        }
        #pragma unroll
        for (int s = 1; s < 64; s <<= 1) {
            p0 += __shfl_xor(p0, s); p1 += __shfl_xor(p1, s); p2 += __shfl_xor(p2, s);
        }
        if (lane == 0) {
            out_xyz[i*3+0] = ctx_xyz[i*3+0] + 0.05f*(cdb2[0] + p0);
            out_xyz[i*3+1] = ctx_xyz[i*3+1] + 0.05f*(cdb2[1] + p1);
            out_xyz[i*3+2] = ctx_xyz[i*3+2] + 0.05f*(cdb2[2] + p2);
        }
    }
}

__global__ __launch_bounds__(64) void edge_dual1_kernel(const float* u, const float* v,
                                                        const float* w2t, const float* b2,
                                                        const int* idx,
                                                        float* h_ctx, float* sq_hctx,
                                                        float* h_tgt, float* sq_htgt, int npts) {
    extern __shared__ float smem[];
    float* st = smem; float* sf_ = smem + 17*192; float* st2_ = sf_ + 96;
    if (blockIdx.y == 0)
        edge_body<192,192,16,0>(st, sf_, st2_, u, v, w2t, b2, idx, 16, h_ctx, sq_hctx,
                                nullptr, nullptr, nullptr, nullptr, nullptr, nullptr, npts);
    else
        edge_body<192,192,4,1>(st, sf_, st2_, u, v, w2t, b2, idx, 16, h_tgt, sq_htgt,
                               nullptr, nullptr, nullptr, nullptr, nullptr, nullptr, npts);
}

__global__ __launch_bounds__(64) void edge_dual2_kernel(const float* u2c, const float* v2c,
                                                        const float* u2t, const float* v2t,
                                                        const float* w2t, const float* b2,
                                                        const int* cidx2, const int* tidx2,
                                                        const float* cdw1, const float* cdb1,
                                                        const float* cdw2, const float* cdb2,
                                                        const float* ctx_xyz, float* out_ctx,
                                                        float* tfeat, int npts) {
    extern __shared__ float smem[];
    float* st = smem; float* sf_ = smem + 17*192; float* st2_ = sf_ + 96;
    if (blockIdx.y == 0)
        edge_body<96,96,8,0>(st, sf_, st2_, u2c, v2c, w2t, b2, cidx2, 8, nullptr, nullptr,
                             cdw1, cdb1, cdw2, cdb2, ctx_xyz, out_ctx, npts);
    else
        edge_body<96,96,2,1>(st, sf_, st2_, u2t, v2t, w2t, b2, tidx2, 2, tfeat, nullptr,
                             nullptr, nullptr, nullptr, nullptr, nullptr, nullptr, npts);
}

// ---------------- refiner EdgeConv (H1=384, H2=3), wave per point ------------------
__global__ __launch_bounds__(256) void edge_ref_kernel(const float* __restrict__ ur,
                                                       const float* __restrict__ vr,
                                                       const float* __restrict__ w2,
                                                       const float* __restrict__ b2,
                                                       const int* __restrict__ idx,
                                                       const float* __restrict__ xyz_in,
                                                       float* __restrict__ out, int n) {
    int wave = threadIdx.x >> 6, lane = threadIdx.x & 63;
    int i = blockIdx.x*4 + wave;
    if (i >= n) return;
    float m0 = -INFF, m1 = -INFF, m2 = -INFF;
    float uh[6];
    #pragma unroll
    for (int t = 0; t < 6; ++t) uh[t] = ur[(size_t)i*384 + lane + 64*t];
    for (int e = 0; e < KRR; ++e) {
        int j = idx[i*KRR + e];
        j = ((unsigned)j < (unsigned)n) ? j : i;
        float a0 = 0.f, a1 = 0.f, a2 = 0.f;
        #pragma unroll
        for (int t = 0; t < 6; ++t) {
            int h = lane + 64*t;
            float tv = frelu(uh[t] + vr[(size_t)j*384 + h]);
            a0 += tv*w2[h*3+0]; a1 += tv*w2[h*3+1]; a2 += tv*w2[h*3+2];
        }
        #pragma unroll
        for (int s = 32; s > 0; s >>= 1) {
            a0 += __shfl_xor(a0, s); a1 += __shfl_xor(a1, s); a2 += __shfl_xor(a2, s);
        }
        m0 = fmaxf(m0, a0 + b2[0]); m1 = fmaxf(m1, a1 + b2[1]); m2 = fmaxf(m2, a2 + b2[2]);
    }
    if (lane == 0) {
        out[i*3+0] = xyz_in[i*3+0] + m0;
        out[i*3+1] = xyz_in[i*3+1] + m1;
        out[i*3+2] = xyz_in[i*3+2] + m2;
    }
}

// ---------------- folding MLP, fused upsample+noise in, xyz1 + packed pts out ------
__global__ __launch_bounds__(256) void fold_kernel(const float* __restrict__ pred_xyz,
                                                   const float* __restrict__ noise,
                                                   const float* __restrict__ featd,
                                                   const float* __restrict__ w1, const float* __restrict__ b1,
                                                   const float* __restrict__ w2, const float* __restrict__ b2,
                                                   const float* __restrict__ w3, const float* __restrict__ b3,
                                                   float* __restrict__ xyz1, float4* __restrict__ pts_out) {
    const int PTS = 16;
    int base = blockIdx.x * PTS;
    int tid = threadIdx.x;
    __shared__ __align__(16) float xin[PTS][100];
    __shared__ __align__(16) float h1[PTS][FOLDH];
    __shared__ __align__(16) float h2s[PTS][FOLDH];
    __shared__ float oxyz[PTS][3];
    for (int t = tid; t < PTS*100; t += 256) {
        int pt = t/100, k = t - pt*100;
        int gi = base + pt;
        float vv = 0.f;
        if (k < 3) {
            int b = gi >> 11, p = (gi & 2047) >> 2;
            vv = pred_xyz[(size_t)(b*PDIM + p)*3 + k] + 0.02f*noise[(size_t)gi*3 + k];
        } else if (k < 99) {
            int b = gi >> 11, p = (gi & 2047) >> 2;
            vv = featd[(size_t)(b*PDIM + p)*H2C + (k - 3)];
        }
        xin[pt][k] = vv;
    }
    __syncthreads();
    int c = tid;
    float acc[PTS];
    #pragma unroll
    for (int pt = 0; pt < PTS; ++pt) acc[pt] = b1[c];
    for (int k0 = 0; k0 < 96; k0 += 4) {
        float wa = w1[(k0+0)*FOLDH + c], wb = w1[(k0+1)*FOLDH + c];
        float wc = w1[(k0+2)*FOLDH + c], wd = w1[(k0+3)*FOLDH + c];
        #pragma unroll
        for (int pt = 0; pt < PTS; ++pt) {
            float4 xv = *(const float4*)&xin[pt][k0];
            acc[pt] += xv.x*wa + xv.y*wb + xv.z*wc + xv.w*wd;
        }
    }
    {
        float wa = w1[96*FOLDH + c], wb = w1[97*FOLDH + c], wc = w1[98*FOLDH + c];
        #pragma unroll
        for (int pt = 0; pt < PTS; ++pt) {
            float4 xv = *(const float4*)&xin[pt][96];
            acc[pt] += xv.x*wa + xv.y*wb + xv.z*wc;
        }
    }
    #pragma unroll
    for (int pt = 0; pt < PTS; ++pt) h1[pt][c] = frelu(acc[pt]);
    __syncthreads();
    #pragma unroll
    for (int pt = 0; pt < PTS; ++pt) acc[pt] = b2[c];
    for (int k0 = 0; k0 < FOLDH; k0 += 4) {
        float wa = w2[(k0+0)*FOLDH + c], wb = w2[(k0+1)*FOLDH + c];
        float wc = w2[(k0+2)*FOLDH + c], wd = w2[(k0+3)*FOLDH + c];
        #pragma unroll
        for (int pt = 0; pt < PTS; ++pt) {
            float4 hv = *(const float4*)&h1[pt][k0];
            acc[pt] += hv.x*wa + hv.y*wb + hv.z*wc + hv.w*wd;
        }
    }
    #pragma unroll
    for (int pt = 0; pt < PTS; ++pt) h2s[pt][c] = frelu(acc[pt]);
    __syncthreads();
    if (tid < PTS*3) {
        int pt = tid/3, cc = tid - pt*3;
        float a = b3[cc];
        for (int k0 = 0; k0 < FOLDH; k0 += 4) {
            float4 hv = *(const float4*)&h2s[pt][k0];
            a += hv.x*w3[(k0+0)*3+cc] + hv.y*w3[(k0+1)*3+cc] + hv.z*w3[(k0+2)*3+cc] + hv.w*w3[(k0+3)*3+cc];
        }
        int gi = base + pt;
        float res = xin[pt][cc] + a;
        xyz1[(size_t)gi*3 + cc] = res;
        oxyz[pt][cc] = res;
    }
    __syncthreads();
    if (tid < PTS) {
        float x = oxyz[tid][0], y = oxyz[tid][1], z = oxyz[tid][2];
        pts_out[base + tid] = make_float4(x, y, z, x*x + y*y + z*z);
    }
}

extern "C" void kernel_launch(void* const* d_in, const int* in_sizes, int n_in,
                              void* d_out, int out_size, void* d_ws, size_t ws_size,
                              hipStream_t stream) {
    const float* ctx_xyz    = (const float*)d_in[0];
    const float* ctx_tokens = (const float*)d_in[1];
    const float* pred_xyz   = (const float*)d_in[2];
    const float* noise      = (const float*)d_in[4];
    const float* c1w1 = (const float*)d_in[5];
    const float* c1b1 = (const float*)d_in[6];
    const float* c1w2 = (const float*)d_in[7];
    const float* c1b2 = (const float*)d_in[8];
    const float* c2w1 = (const float*)d_in[9];
    const float* c2b1 = (const float*)d_in[10];
    const float* c2w2 = (const float*)d_in[11];
    const float* c2b2 = (const float*)d_in[12];
    const float* cdw1 = (const float*)d_in[13];
    const float* cdb1 = (const float*)d_in[14];
    const float* cdw2 = (const float*)d_in[15];
    const float* cdb2 = (const float*)d_in[16];
    const float* fw1  = (const float*)d_in[17];
    const float* fb1  = (const float*)d_in[18];
    const float* fw2  = (const float*)d_in[19];
    const float* fb2  = (const float*)d_in[20];
    const float* fw3  = (const float*)d_in[21];
    const float* fb3  = (const float*)d_in[22];
    const float* rw1  = (const float*)d_in[23];
    const float* rb1  = (const float*)d_in[24];
    const float* rw2  = (const float*)d_in[25];
    const float* rb2  = (const float*)d_in[26];

    float* W = (float*)d_ws;
    // region A (aliased over time): dist (S1/S3/S4) -> pts (S6/S7) -> ur (S8)
    float* dist = W;                          // 2048*2048 = 4,194,304
    float4* pts = (float4*)W;                 // 8192 float4
    float* ur   = W;                          // 8192*384
    float* vr   = W + 3145728;                // ..6,291,456 (written S8; overlaps only dead bufs)
    // region T (transient, dead before vr written)
    float* u1    = W + 4194304;               // 2048*192
    float* v1    = u1 + N2*H1C;
    float* h_ctx = v1 + N2*H1C;
    float* h_tgt = h_ctx + N2*H1C;
    float* u2c   = h_tgt + N2*H1C;            // 2048*96 each
    float* v2c   = u2c + N2*H2C;
    float* u2t   = v2c + N2*H2C;
    float* v2t   = u2t + N2*H2C;              // ends 6,553,600
    // region P (persistent past vr)
    float* tfeat   = W + 6553600;             // 2048*96
    float* sqb     = tfeat + N2*H2C;
    float* sq_hctx = sqb + N2;
    float* sq_htgt = sq_hctx + N2;
    float* xyz1    = sq_htgt + N2;            // 8192*3
    int*   cidx1   = (int*)(xyz1 + N8*3);     // 2048*16
    int*   cidx2   = cidx1 + N2*16;           // 2048*8
    int*   tidx2   = cidx2 + N2*8;            // 2048*2
    int*   ridx    = tidx2 + N2*2;            // 8192*16 -> ends elem 6,965,248
    float* w2t1    = W + 6965248;             // 192*192 = 36,864
    float* w2t2    = w2t1 + 192*192;          // 96*96 = 9,216 -> ends 7,011,328
    float* distB   = W + 7011328;             // second dist buffer
    bool hasB = ws_size >= (size_t)(7011328 + 4194304) * 4;

    float* out_ctx = (float*)d_out;
    float* out_tgt = out_ctx + N2*3;

    dim3 b16(16, 16);
    const size_t ESM = (17*192 + 192) * sizeof(float);
    const int NTRI = 32*33/2;   // 528 triangular tiles
    const float* NUL = nullptr;

    // --- prep: rowsq(tokens) + w2 transposes
    rowsq_kernel<<<N2/4, 256, 0, stream>>>(ctx_tokens, sqb, CDIM);
    wtrans_kernel<<<dim3(144, 2), 256, 0, stream>>>(c1w2, w2t1, c2w2, w2t2);

    // --- S1: dist(tokens) triangular; knn16 (tidx1 == first 4 of cidx1)
    dist64tri_kernel<<<NTRI, b16, 0, stream>>>(ctx_tokens, sqb, dist, N2, CDIM);
    knn_dist_rt_kernel<<<N2/4, 256, 0, stream>>>(dist, dist, N2, cidx1, cidx1, 16, 16, N2/4);

    // --- S2: u1/v1 GEMMs (z-paired), dual conv1
    gemmquad_kernel<<<dim3(3, 32, 2), b16, 0, stream>>>(
        ctx_tokens, c1w1, c1w1 + 384*192, c1b1, u1,
        ctx_tokens, c1w1 + 384*192, NUL, NUL, v1,
        ctx_tokens, c1w1, NUL, NUL, u1,   // unused (z<2)
        ctx_tokens, c1w1, NUL, NUL, v1,
        H1C, CDIM);
    edge_dual1_kernel<<<dim3(N2, 2), 64, ESM, stream>>>(u1, v1, w2t1, c1b2, cidx1,
                                                        h_ctx, sq_hctx, h_tgt, sq_htgt, N2);

    // --- S3/S4: dist(h_ctx)+dist(h_tgt) triangular, paired knn, u2/v2 quad, conv2
    if (hasB) {
        distpairtri_kernel<<<dim3(NTRI, 1, 2), b16, 0, stream>>>(h_ctx, sq_hctx, dist,
                                                                 h_tgt, sq_htgt, distB, N2, H1C);
        knn_dist_rt_kernel<<<2*(N2/4), 256, 0, stream>>>(dist, distB, N2, cidx2, tidx2, 8, 2, N2/4);
    } else {
        dist64tri_kernel<<<NTRI, b16, 0, stream>>>(h_ctx, sq_hctx, dist, N2, H1C);
        knn_dist_rt_kernel<<<N2/4, 256, 0, stream>>>(dist, dist, N2, cidx2, cidx2, 8, 8, N2/4);
        dist64tri_kernel<<<NTRI, b16, 0, stream>>>(h_tgt, sq_htgt, dist, N2, H1C);
        knn_dist_rt_kernel<<<N2/4, 256, 0, stream>>>(dist, dist, N2, tidx2, tidx2, 2, 2, N2/4);
    }
    gemmquad_kernel<<<dim3(2, 32, 4), b16, 0, stream>>>(
        h_ctx, c2w1, c2w1 + 192*96, c2b1, u2c,
        h_ctx, c2w1 + 192*96, NUL, NUL, v2c,
        h_tgt, c2w1, c2w1 + 192*96, c2b1, u2t,
        h_tgt, c2w1 + 192*96, NUL, NUL, v2t,
        H2C, H1C);
    edge_dual2_kernel<<<dim3(N2, 2), 64, ESM, stream>>>(u2c, v2c, u2t, v2t, w2t2, c2b2,
                                                        cidx2, tidx2, cdw1, cdb1, cdw2, cdb2,
                                                        ctx_xyz, out_ctx, tfeat, N2);

    // --- S6: folding MLP (fused upsample+noise; emits xyz1 + packed pts)
    fold_kernel<<<N8/16, 256, 0, stream>>>(pred_xyz, noise, tfeat, fw1, fb1, fw2, fb2, fw3, fb3, xyz1, pts);

    // --- S7: refiner knn (8 rows/block, bitonic select)
    knn_xyz8_kernel<<<N8/8, 256, 0, stream>>>(pts, N8, ridx);

    // --- S8: refiner u/v gather-GEMMs (z-paired), residual EdgeConv to output
    gatherpair_kernel<<<dim3(6, N8/64, 2), b16, 0, stream>>>(
        tfeat, xyz1,
        rw1, rw1 + 99*384, rb1, ur,
        rw1 + 99*384, NUL, NUL, vr,
        384, 99);
    edge_ref_kernel<<<N8/4, 256, 0, stream>>>(ur, vr, rw2, rb2, ridx, xyz1, out_tgt, N8);
}

// Round 9
// 535.776 us; speedup vs baseline: 1.5257x; 1.5257x over previous
//
#include <hip/hip_runtime.h>

#define N2 2048      // B*P
#define N8 8192      // B*P*UP
#define CDIM 384
#define H1C 192      // C/2
#define H2C 96       // C/4
#define PDIM 512
#define KRR 16
#define FOLDH 256
#define XCAP 256
#define XTILE 1024
#define INFF 3.0e38f

__device__ __forceinline__ float frelu(float x) { return x > 0.f ? x : 0.f; }

// ---------------- 64-lane bitonic sorts (ascending) --------------------------------
__device__ __forceinline__ void bitonic64_val(float& d, int lane) {
    #pragma unroll
    for (int k = 2; k <= 64; k <<= 1) {
        #pragma unroll
        for (int j = k >> 1; j > 0; j >>= 1) {
            float od = __shfl_xor(d, j);
            bool lower = (lane & j) == 0;
            bool olt = od < d;
            bool take = lower ? olt : !olt;
            if (lane & k) take = !take;
            if (take) d = od;
        }
    }
}

__device__ __forceinline__ void bitonic64_pair(float& d, int& c, int lane) {
    #pragma unroll
    for (int k = 2; k <= 64; k <<= 1) {
        #pragma unroll
        for (int j = k >> 1; j > 0; j >>= 1) {
            float od = __shfl_xor(d, j);
            int   oc = __shfl_xor(c, j);
            bool lower = (lane & j) == 0;
            bool olt = (od < d) || (od == d && oc < c);
            bool take = lower ? olt : !olt;
            if (lane & k) take = !take;
            if (take) { d = od; c = oc; }
        }
    }
}

// ---------------- slow exact select fallback (cnt > 64, rare) ----------------------
__device__ __forceinline__ void select_slow(const float* bd, const int* bi, int cnt,
                                            int ksel, int row, int n, int* out, int lane) {
    float cd[4]; int cix[4];
    #pragma unroll
    for (int s = 0; s < 4; ++s) {
        int c = lane + 64*s;
        bool v = c < cnt;
        cd[s]  = v ? bd[c] : INFF;
        cix[s] = v ? bi[c] : 0x7fffffff;
    }
    for (int r = 0; r < ksel; ++r) {
        float lv = cd[0]; int li = cix[0];
        #pragma unroll
        for (int s = 1; s < 4; ++s) {
            if (cd[s] < lv || (cd[s] == lv && cix[s] < li)) { lv = cd[s]; li = cix[s]; }
        }
        float wv = lv; int wi = li;
        #pragma unroll
        for (int s = 1; s < 64; s <<= 1) {
            float ov = __shfl_xor(wv, s); int oi = __shfl_xor(wi, s);
            if (ov < wv || (ov == wv && oi < wi)) { wv = ov; wi = oi; }
        }
        if (lane == 0) {
            int safe = ((unsigned)wi < (unsigned)n) ? wi : ((row + 1) & (n - 1));
            out[row*ksel + r] = safe;
        }
        #pragma unroll
        for (int s = 0; s < 4; ++s) {
            if (cd[s] == wv && cix[s] == wi) { cd[s] = INFF; cix[s] = 0x7fffffff; }
        }
    }
}

// ---------------- row squared norms (wave per row) ---------------------------------
__global__ __launch_bounds__(256) void rowsq_kernel(const float* __restrict__ x,
                                                    float* __restrict__ sq, int d) {
    int wave = threadIdx.x >> 6, lane = threadIdx.x & 63;
    int row = blockIdx.x*4 + wave;
    float acc = 0.f;
    for (int k = lane; k < d; k += 64) { float v = x[(size_t)row*d + k]; acc += v*v; }
    #pragma unroll
    for (int s = 1; s < 64; s <<= 1) acc += __shfl_xor(acc, s);
    if (lane == 0) sq[row] = acc;
}

// ---------------- weight transposes (c1w2 192x192, c2w2 96x96) ---------------------
__global__ __launch_bounds__(256) void wtrans_kernel(const float* __restrict__ w1, float* __restrict__ o1,
                                                     const float* __restrict__ w2, float* __restrict__ o2) {
    int i = blockIdx.x*256 + threadIdx.x;
    if (blockIdx.y == 0) {
        if (i < 192*192) { int h = i / 192, c = i - h*192; o1[c*192 + h] = w1[i]; }
    } else {
        if (i < 96*96) { int h = i / 96, c = i - h*96; o2[c*96 + h] = w2[i]; }
    }
}

// ---------------- triangular symmetric dist: direct + mirrored tile ----------------
__device__ __forceinline__ void disttri_body(const float* __restrict__ x, const float* __restrict__ sq,
                                             float* __restrict__ dist, int n, int K) {
    int l = blockIdx.x;
    int by = (int)((sqrtf(8.f*(float)l + 1.f) - 1.f)*0.5f);
    while ((by+1)*(by+2)/2 <= l) ++by;
    while (by*(by+1)/2 > l) --by;
    int bx = l - by*(by+1)/2;
    int row0 = by*64, col0 = bx*64;
    __shared__ __align__(16) float As[16][68];
    __shared__ __align__(16) float Bs[16][68];
    __shared__ __align__(16) float T[64][68];
    int tx = threadIdx.x, ty = threadIdx.y;
    int t = ty*16 + tx;
    float acc[4][4] = {};
    for (int k0 = 0; k0 < K; k0 += 16) {
        #pragma unroll
        for (int r = 0; r < 4; ++r) {
            int e = t + 256*r; int kk = e & 15, mm = e >> 4;
            As[kk][mm] = x[(size_t)(row0+mm)*K + k0+kk];
            Bs[kk][mm] = x[(size_t)(col0+mm)*K + k0+kk];
        }
        __syncthreads();
        #pragma unroll
        for (int kk = 0; kk < 16; ++kk) {
            float4 a4 = *(const float4*)&As[kk][ty*4];
            float4 b4 = *(const float4*)&Bs[kk][tx*4];
            acc[0][0] += a4.x*b4.x; acc[0][1] += a4.x*b4.y; acc[0][2] += a4.x*b4.z; acc[0][3] += a4.x*b4.w;
            acc[1][0] += a4.y*b4.x; acc[1][1] += a4.y*b4.y; acc[1][2] += a4.y*b4.z; acc[1][3] += a4.y*b4.w;
            acc[2][0] += a4.z*b4.x; acc[2][1] += a4.z*b4.y; acc[2][2] += a4.z*b4.z; acc[2][3] += a4.z*b4.w;
            acc[3][0] += a4.w*b4.x; acc[3][1] += a4.w*b4.y; acc[3][2] += a4.w*b4.z; acc[3][3] += a4.w*b4.w;
        }
        __syncthreads();
    }
    bool mirror = (row0 != col0);
    #pragma unroll
    for (int i2 = 0; i2 < 4; ++i2) {
        int row = row0 + ty*4 + i2;
        float sr = sq[row];
        float4 o;
        o.x = sr + sq[col0+tx*4+0] - 2.f*acc[i2][0];
        o.y = sr + sq[col0+tx*4+1] - 2.f*acc[i2][1];
        o.z = sr + sq[col0+tx*4+2] - 2.f*acc[i2][2];
        o.w = sr + sq[col0+tx*4+3] - 2.f*acc[i2][3];
        *(float4*)&dist[(size_t)row*n + col0 + tx*4] = o;
        if (mirror) {
            T[tx*4+0][ty*4+i2] = o.x;
            T[tx*4+1][ty*4+i2] = o.y;
            T[tx*4+2][ty*4+i2] = o.z;
            T[tx*4+3][ty*4+i2] = o.w;
        }
    }
    if (mirror) {
        __syncthreads();
        #pragma unroll
        for (int i2 = 0; i2 < 4; ++i2) {
            int orow = col0 + ty*4 + i2;
            float4 o = *(const float4*)&T[ty*4+i2][tx*4];
            *(float4*)&dist[(size_t)orow*n + row0 + tx*4] = o;
        }
    }
}

__global__ __launch_bounds__(256) void dist64tri_kernel(const float* __restrict__ x,
                                                        const float* __restrict__ sq,
                                                        float* __restrict__ dist, int n, int K) {
    disttri_body(x, sq, dist, n, K);
}

__global__ __launch_bounds__(256) void distpairtri_kernel(const float* __restrict__ xA,
                                                          const float* __restrict__ sqA,
                                                          float* __restrict__ dA,
                                                          const float* __restrict__ xB,
                                                          const float* __restrict__ sqB,
                                                          float* __restrict__ dB, int n, int K) {
    const float* x  = blockIdx.z ? xB : xA;
    const float* sq = blockIdx.z ? sqB : sqA;
    float* dist     = blockIdx.z ? dB : dA;
    disttri_body(x, sq, dist, n, K);
}

// ---------------- shared 64x64 GEMM tile body: C = A @ (Bw - BwB) + bias -----------
__device__ __forceinline__ void gemm_body(const float* __restrict__ A, const float* __restrict__ Bw,
                                          const float* __restrict__ BwB, const float* __restrict__ bias,
                                          float* __restrict__ C, int m, int K) {
    __shared__ __align__(16) float As[16][68];
    __shared__ __align__(16) float Bs[16][68];
    int tx = threadIdx.x, ty = threadIdx.y;
    int t = ty*16 + tx;
    int row0 = blockIdx.y*64, col0 = blockIdx.x*64;
    float acc[4][4] = {};
    for (int k0 = 0; k0 < K; k0 += 16) {
        #pragma unroll
        for (int r = 0; r < 4; ++r) {
            int e = t + 256*r; int kk = e & 15, mm = e >> 4;
            As[kk][mm] = (k0 + kk < K) ? A[(size_t)(row0+mm)*K + k0+kk] : 0.f;
        }
        #pragma unroll
        for (int r = 0; r < 4; ++r) {
            int e = t + 256*r; int nn = e & 63, kk = e >> 6;
            int col = col0 + nn, k = k0 + kk;
            float bv = 0.f;
            if (k < K && col < m) {
                bv = Bw[(size_t)k*m + col];
                if (BwB) bv -= BwB[(size_t)k*m + col];
            }
            Bs[kk][nn] = bv;
        }
        __syncthreads();
        #pragma unroll
        for (int kk = 0; kk < 16; ++kk) {
            float4 a4 = *(const float4*)&As[kk][ty*4];
            float4 b4 = *(const float4*)&Bs[kk][tx*4];
            acc[0][0] += a4.x*b4.x; acc[0][1] += a4.x*b4.y; acc[0][2] += a4.x*b4.z; acc[0][3] += a4.x*b4.w;
            acc[1][0] += a4.y*b4.x; acc[1][1] += a4.y*b4.y; acc[1][2] += a4.y*b4.z; acc[1][3] += a4.y*b4.w;
            acc[2][0] += a4.z*b4.x; acc[2][1] += a4.z*b4.y; acc[2][2] += a4.z*b4.z; acc[2][3] += a4.z*b4.w;
            acc[3][0] += a4.w*b4.x; acc[3][1] += a4.w*b4.y; acc[3][2] += a4.w*b4.z; acc[3][3] += a4.w*b4.w;
        }
        __syncthreads();
    }
    #pragma unroll
    for (int i2 = 0; i2 < 4; ++i2) {
        int row = row0 + ty*4 + i2;
        #pragma unroll
        for (int j2 = 0; j2 < 4; ++j2) {
            int col = col0 + tx*4 + j2;
            if (col < m) C[(size_t)row*m + col] = acc[i2][j2] + (bias ? bias[col] : 0.f);
        }
    }
}

__global__ __launch_bounds__(256) void gemmquad_kernel(
    const float* A0, const float* Bw0, const float* BwB0, const float* bias0, float* C0,
    const float* A1, const float* Bw1, const float* BwB1, const float* bias1, float* C1,
    const float* A2, const float* Bw2, const float* BwB2, const float* bias2, float* C2,
    const float* A3, const float* Bw3, const float* BwB3, const float* bias3, float* C3,
    int m, int K) {
    int z = blockIdx.z;
    const float* A    = (z==0)?A0 :(z==1)?A1 :(z==2)?A2 :A3;
    const float* Bw   = (z==0)?Bw0:(z==1)?Bw1:(z==2)?Bw2:Bw3;
    const float* BwB  = (z==0)?BwB0:(z==1)?BwB1:(z==2)?BwB2:BwB3;
    const float* bias = (z==0)?bias0:(z==1)?bias1:(z==2)?bias2:bias3;
    float* C          = (z==0)?C0 :(z==1)?C1 :(z==2)?C2 :C3;
    gemm_body(A, Bw, BwB, bias, C, m, K);
}

// refiner gather-GEMM pair: A row gathered from [featd(96) | xyzg(3)], K = 99
__global__ __launch_bounds__(256) void gatherpair_kernel(
    const float* __restrict__ featd, const float* __restrict__ xyzg,
    const float* Bw0, const float* BwB0, const float* bias0, float* C0,
    const float* Bw1, const float* BwB1, const float* bias1, float* C1,
    int m, int K) {
    int z = blockIdx.z;
    const float* Bw   = z ? Bw1 : Bw0;
    const float* BwB  = z ? BwB1 : BwB0;
    const float* bias = z ? bias1 : bias0;
    float* C          = z ? C1 : C0;
    __shared__ __align__(16) float As[16][68];
    __shared__ __align__(16) float Bs[16][68];
    int tx = threadIdx.x, ty = threadIdx.y;
    int t = ty*16 + tx;
    int row0 = blockIdx.y*64, col0 = blockIdx.x*64;
    float acc[4][4] = {};
    for (int k0 = 0; k0 < K; k0 += 16) {
        #pragma unroll
        for (int r = 0; r < 4; ++r) {
            int e = t + 256*r; int kk = e & 15, mm = e >> 4;
            int k = k0 + kk, grow = row0 + mm;
            float av = 0.f;
            if (k < K) {
                if (k < 96) { int b = grow >> 11, p = (grow & 2047) >> 2;
                              av = featd[(size_t)(b*PDIM + p)*H2C + k]; }
                else av = xyzg[(size_t)grow*3 + (k - 96)];
            }
            As[kk][mm] = av;
        }
        #pragma unroll
        for (int r = 0; r < 4; ++r) {
            int e = t + 256*r; int nn = e & 63, kk = e >> 6;
            int col = col0 + nn, k = k0 + kk;
            float bv = 0.f;
            if (k < K && col < m) {
                bv = Bw[(size_t)k*m + col];
                if (BwB) bv -= BwB[(size_t)k*m + col];
            }
            Bs[kk][nn] = bv;
        }
        __syncthreads();
        #pragma unroll
        for (int kk = 0; kk < 16; ++kk) {
            float4 a4 = *(const float4*)&As[kk][ty*4];
            float4 b4 = *(const float4*)&Bs[kk][tx*4];
            acc[0][0] += a4.x*b4.x; acc[0][1] += a4.x*b4.y; acc[0][2] += a4.x*b4.z; acc[0][3] += a4.x*b4.w;
            acc[1][0] += a4.y*b4.x; acc[1][1] += a4.y*b4.y; acc[1][2] += a4.y*b4.z; acc[1][3] += a4.y*b4.w;
            acc[2][0] += a4.z*b4.x; acc[2][1] += a4.z*b4.y; acc[2][2] += a4.z*b4.z; acc[2][3] += a4.z*b4.w;
            acc[3][0] += a4.w*b4.x; acc[3][1] += a4.w*b4.y; acc[3][2] += a4.w*b4.z; acc[3][3] += a4.w*b4.w;
        }
        __syncthreads();
    }
    #pragma unroll
    for (int i2 = 0; i2 < 4; ++i2) {
        int row = row0 + ty*4 + i2;
        #pragma unroll
        for (int j2 = 0; j2 < 4; ++j2) {
            int col = col0 + tx*4 + j2;
            if (col < m) C[(size_t)row*m + col] = acc[i2][j2] + (bias ? bias[col] : 0.f);
        }
    }
}

// ---------------- knn from dist rows (4 rows/block, bitonic select) ----------------
__global__ __launch_bounds__(256) void knn_dist_rt_kernel(const float* __restrict__ dA,
                                                          const float* __restrict__ dB, int n,
                                                          int* __restrict__ outA, int* __restrict__ outB,
                                                          int kA, int kB, int nblkA) {
    int wave = threadIdx.x >> 6, lane = threadIdx.x & 63;
    bool useB = (int)blockIdx.x >= nblkA;
    const float* dist = useB ? dB : dA;
    int* out = useB ? outB : outA;
    int ksel = useB ? kB : kA;
    int bx = useB ? (int)blockIdx.x - nblkA : (int)blockIdx.x;
    int row = bx*4 + wave;
    __shared__ float bufd[4][XCAP];
    __shared__ int   bufi[4][XCAP];
    __shared__ int   lcnt[4];
    const float4* drow = (const float4*)(dist + (size_t)row*n);
    int nq = n >> 2;
    float mv = INFF;
    for (int i = lane; i < nq; i += 64) {
        float4 d4 = drow[i]; int base = i*4;
        float a = (base+0 == row) ? INFF : d4.x;
        float b = (base+1 == row) ? INFF : d4.y;
        float c = (base+2 == row) ? INFF : d4.z;
        float d = (base+3 == row) ? INFF : d4.w;
        mv = fminf(mv, fminf(fminf(a,b), fminf(c,d)));
    }
    float sd = mv;
    bitonic64_val(sd, lane);
    float Tv = __shfl(sd, ksel - 1);
    if (lane == 0) lcnt[wave] = 0;
    for (int i = lane; i < nq; i += 64) {
        float4 d4 = drow[i]; int base = i*4;
        float dv4[4] = {d4.x, d4.y, d4.z, d4.w};
        #pragma unroll
        for (int q = 0; q < 4; ++q) {
            int col = base + q;
            if (col != row && dv4[q] <= Tv) {
                int pos = atomicAdd(&lcnt[wave], 1);
                if (pos < XCAP) { bufd[wave][pos] = dv4[q]; bufi[wave][pos] = col; }
            }
        }
    }
    int cnt = lcnt[wave]; if (cnt > XCAP) cnt = XCAP;
    if (cnt <= 64) {
        float d = (lane < cnt) ? bufd[wave][lane] : INFF;
        int   c = (lane < cnt) ? bufi[wave][lane] : 0x7fffffff;
        bitonic64_pair(d, c, lane);
        if (lane < ksel) {
            int safe = ((unsigned)c < (unsigned)n) ? c : ((row + 1) & (n - 1));
            out[row*ksel + lane] = safe;
        }
    } else {
        select_slow(bufd[wave], bufi[wave], cnt, ksel, row, n, out, lane);
    }
}

// ---------------- knn over packed xyz: 8 rows/block, 2 rows/wave -------------------
__global__ __launch_bounds__(256) void knn_xyz8_kernel(const float4* __restrict__ pts, int n,
                                                       int* __restrict__ out_idx) {
    int tid = threadIdx.x, wave = tid >> 6, lane = tid & 63;
    int rbase = blockIdx.x*8 + wave*2;
    __shared__ __align__(16) float4 tile[XTILE];
    __shared__ float bufd[8][XCAP];
    __shared__ int   bufi[8][XCAP];
    __shared__ int   lcnt[8];
    float4 P0 = pts[rbase], P1 = pts[rbase + 1];
    float mv0 = INFF, mv1 = INFF;
    for (int t0 = 0; t0 < n; t0 += XTILE) {
        __syncthreads();
        #pragma unroll
        for (int k = 0; k < XTILE/256; ++k) tile[tid + 256*k] = pts[t0 + tid + 256*k];
        __syncthreads();
        for (int c = lane; c < XTILE; c += 64) {
            float4 q = tile[c];
            int col = t0 + c;
            float d0 = P0.w + q.w - 2.f*(P0.x*q.x + P0.y*q.y + P0.z*q.z);
            float d1 = P1.w + q.w - 2.f*(P1.x*q.x + P1.y*q.y + P1.z*q.z);
            d0 = (col == rbase)     ? INFF : d0;
            d1 = (col == rbase + 1) ? INFF : d1;
            mv0 = fminf(mv0, d0);
            mv1 = fminf(mv1, d1);
        }
    }
    float s0 = mv0, s1 = mv1;
    bitonic64_val(s0, lane);
    bitonic64_val(s1, lane);
    float Tv0 = __shfl(s0, 15);
    float Tv1 = __shfl(s1, 15);
    if (lane < 2) lcnt[wave*2 + lane] = 0;
    for (int t0 = 0; t0 < n; t0 += XTILE) {
        __syncthreads();
        #pragma unroll
        for (int k = 0; k < XTILE/256; ++k) tile[tid + 256*k] = pts[t0 + tid + 256*k];
        __syncthreads();
        for (int c = lane; c < XTILE; c += 64) {
            float4 q = tile[c];
            int col = t0 + c;
            float d0 = P0.w + q.w - 2.f*(P0.x*q.x + P0.y*q.y + P0.z*q.z);
            float d1 = P1.w + q.w - 2.f*(P1.x*q.x + P1.y*q.y + P1.z*q.z);
            if (col != rbase && d0 <= Tv0) {
                int pos = atomicAdd(&lcnt[wave*2], 1);
                if (pos < XCAP) { bufd[wave*2][pos] = d0; bufi[wave*2][pos] = col; }
            }
            if (col != rbase + 1 && d1 <= Tv1) {
                int pos = atomicAdd(&lcnt[wave*2 + 1], 1);
                if (pos < XCAP) { bufd[wave*2 + 1][pos] = d1; bufi[wave*2 + 1][pos] = col; }
            }
        }
    }
    for (int jj = 0; jj < 2; ++jj) {
        int brow = wave*2 + jj, row = rbase + jj;
        int cnt = lcnt[brow]; if (cnt > XCAP) cnt = XCAP;
        if (cnt <= 64) {
            float d = (lane < cnt) ? bufd[brow][lane] : INFF;
            int   c = (lane < cnt) ? bufi[brow][lane] : 0x7fffffff;
            bitonic64_pair(d, c, lane);
            if (lane < 16) {
                int safe = ((unsigned)c < (unsigned)n) ? c : ((row + 1) & (n - 1));
                out_idx[row*16 + lane] = safe;
            }
        } else {
            select_slow(bufd[brow], bufi[brow], cnt, 16, row, n, out_idx, lane);
        }
    }
}

// ---------------- EdgeConv: one column per thread, bounded registers ---------------
// Block = BLK threads (BLK >= H2); thread tid owns output column tid (guarded).
// acc[E] only; h-loop not unrolled -> no register explosion, no scratch.
template<int H1, int H2, int KN, int SELF, int BLK>
__device__ __forceinline__ void edge_body_cw(float* su, float* st, float* pmsq, int* jarr,
                                             float* sf_, float* st2_,
                                             const float* __restrict__ u, const float* __restrict__ v,
                                             const float* __restrict__ w2t, const float* __restrict__ b2,
                                             const int* __restrict__ idx, int idxs,
                                             float* __restrict__ out, float* __restrict__ out_sq,
                                             const float* __restrict__ cdw1, const float* __restrict__ cdb1,
                                             const float* __restrict__ cdw2, const float* __restrict__ cdb2,
                                             const float* __restrict__ ctx_xyz, float* __restrict__ out_xyz,
                                             int npts) {
    constexpr int E = KN + SELF;
    constexpr int NW = BLK / 64;
    int i = blockIdx.x;
    int tid = threadIdx.x, wave = tid >> 6, lane = tid & 63;
    for (int h = tid; h < H1; h += BLK) su[h] = u[(size_t)i*H1 + h];
    if (tid < E) {
        int e = tid;
        int j = (SELF && e == 0) ? i : idx[i*idxs + (e - SELF)];
        jarr[e] = ((unsigned)j < (unsigned)npts) ? j : i;
    }
    __syncthreads();
    for (int t = tid; t < E*H1; t += BLK) {
        int e = t / H1, h = t - e*H1;
        st[t] = frelu(su[h] + v[(size_t)jarr[e]*H1 + h]);
    }
    __syncthreads();
    int col = tid;
    int colc = (col < H2) ? col : 0;    // safe address for inactive threads
    float acc[E];
    #pragma unroll
    for (int e = 0; e < E; ++e) acc[e] = 0.f;
    #pragma unroll 1
    for (int h0 = 0; h0 < H1; h0 += 4) {
        float4 w4 = *(const float4*)&w2t[(size_t)colc*H1 + h0];
        #pragma unroll
        for (int e = 0; e < E; ++e) {
            float4 s4 = *(const float4*)&st[e*H1 + h0];
            acc[e] += s4.x*w4.x + s4.y*w4.y + s4.z*w4.z + s4.w*w4.w;
        }
    }
    float best = acc[0];
    #pragma unroll
    for (int e = 1; e < E; ++e) best = fmaxf(best, acc[e]);
    float val = (col < H2) ? best + b2[col] : 0.f;
    if (out && col < H2) out[(size_t)i*H2 + col] = val;
    if (out_sq) {
        float part = val*val;
        #pragma unroll
        for (int s = 1; s < 64; s <<= 1) part += __shfl_xor(part, s);
        if (lane == 0) pmsq[wave] = part;
        __syncthreads();
        if (tid == 0) {
            float sq = pmsq[0];
            #pragma unroll
            for (int w = 1; w < NW; ++w) sq += pmsq[w];
            out_sq[i] = sq;
        }
    }
    if (H2 == 96 && cdw1) {
        if (col < 96) sf_[col] = val;
        __syncthreads();
        if (tid < 96) {
            float a = cdb1[tid];
            for (int k = 0; k < 96; ++k) a += sf_[k]*cdw1[k*96 + tid];
            st2_[tid] = frelu(a);
        }
        __syncthreads();
        if (wave == 0) {
            float s0 = st2_[lane];
            float p0 = s0*cdw2[lane*3+0], p1 = s0*cdw2[lane*3+1], p2 = s0*cdw2[lane*3+2];
            if (lane < 32) {
                float s1 = st2_[lane+64];
                p0 += s1*cdw2[(lane+64)*3+0];
                p1 += s1*cdw2[(lane+64)*3+1];
                p2 += s1*cdw2[(lane+64)*3+2];
            }
            #pragma unroll
            for (int s = 1; s < 64; s <<= 1) {
                p0 += __shfl_xor(p0, s); p1 += __shfl_xor(p1, s); p2 += __shfl_xor(p2, s);
            }
            if (lane == 0) {
                out_xyz[i*3+0] = ctx_xyz[i*3+0] + 0.05f*(cdb2[0] + p0);
                out_xyz[i*3+1] = ctx_xyz[i*3+1] + 0.05f*(cdb2[1] + p1);
                out_xyz[i*3+2] = ctx_xyz[i*3+2] + 0.05f*(cdb2[2] + p2);
            }
        }
    }
}

__global__ __launch_bounds__(192) void edge_quad1_kernel(const float* u, const float* v,
                                                         const float* w2t, const float* b2,
                                                         const int* idx,
                                                         float* h_ctx, float* sq_hctx,
                                                         float* h_tgt, float* sq_htgt, int npts) {
    extern __shared__ float smem[];
    float* su = smem;                 // 192
    float* st = su + 192;             // 16*192 max
    float* pmsq = st + 16*192;        // 4
    int*   jarr = (int*)(pmsq + 4);   // 16
    float* sf_  = (float*)(jarr + 16);
    float* st2_ = sf_ + 96;
    if (blockIdx.y == 0)
        edge_body_cw<192,192,16,0,192>(su, st, pmsq, jarr, sf_, st2_, u, v, w2t, b2, idx, 16,
                                       h_ctx, sq_hctx, nullptr, nullptr, nullptr, nullptr,
                                       nullptr, nullptr, npts);
    else
        edge_body_cw<192,192,4,1,192>(su, st, pmsq, jarr, sf_, st2_, u, v, w2t, b2, idx, 16,
                                      h_tgt, sq_htgt, nullptr, nullptr, nullptr, nullptr,
                                      nullptr, nullptr, npts);
}

__global__ __launch_bounds__(128) void edge_quad2_kernel(const float* u2c, const float* v2c,
                                                         const float* u2t, const float* v2t,
                                                         const float* w2t, const float* b2,
                                                         const int* cidx2, const int* tidx2,
                                                         const float* cdw1, const float* cdb1,
                                                         const float* cdw2, const float* cdb2,
                                                         const float* ctx_xyz, float* out_ctx,
                                                         float* tfeat, int npts) {
    extern __shared__ float smem[];
    float* su = smem;                 // 96
    float* st = su + 96;              // 8*96 max
    float* pmsq = st + 8*96;          // 4
    int*   jarr = (int*)(pmsq + 4);   // 8
    float* sf_  = (float*)(jarr + 8);
    float* st2_ = sf_ + 96;
    if (blockIdx.y == 0)
        edge_body_cw<96,96,8,0,128>(su, st, pmsq, jarr, sf_, st2_, u2c, v2c, w2t, b2, cidx2, 8,
                                    nullptr, nullptr, cdw1, cdb1, cdw2, cdb2,
                                    ctx_xyz, out_ctx, npts);
    else
        edge_body_cw<96,96,2,1,128>(su, st, pmsq, jarr, sf_, st2_, u2t, v2t, w2t, b2, tidx2, 2,
                                    tfeat, nullptr, nullptr, nullptr, nullptr, nullptr,
                                    nullptr, nullptr, npts);
}

// ---------------- refiner EdgeConv (H1=384, H2=3), wave per point ------------------
__global__ __launch_bounds__(256) void edge_ref_kernel(const float* __restrict__ ur,
                                                       const float* __restrict__ vr,
                                                       const float* __restrict__ w2,
                                                       const float* __restrict__ b2,
                                                       const int* __restrict__ idx,
                                                       const float* __restrict__ xyz_in,
                                                       float* __restrict__ out, int n) {
    int wave = threadIdx.x >> 6, lane = threadIdx.x & 63;
    int i = blockIdx.x*4 + wave;
    if (i >= n) return;
    float m0 = -INFF, m1 = -INFF, m2 = -INFF;
    float uh[6];
    #pragma unroll
    for (int t = 0; t < 6; ++t) uh[t] = ur[(size_t)i*384 + lane + 64*t];
    for (int e = 0; e < KRR; ++e) {
        int j = idx[i*KRR + e];
        j = ((unsigned)j < (unsigned)n) ? j : i;
        float a0 = 0.f, a1 = 0.f, a2 = 0.f;
        #pragma unroll
        for (int t = 0; t < 6; ++t) {
            int h = lane + 64*t;
            float tv = frelu(uh[t] + vr[(size_t)j*384 + h]);
            a0 += tv*w2[h*3+0]; a1 += tv*w2[h*3+1]; a2 += tv*w2[h*3+2];
        }
        #pragma unroll
        for (int s = 32; s > 0; s >>= 1) {
            a0 += __shfl_xor(a0, s); a1 += __shfl_xor(a1, s); a2 += __shfl_xor(a2, s);
        }
        m0 = fmaxf(m0, a0 + b2[0]); m1 = fmaxf(m1, a1 + b2[1]); m2 = fmaxf(m2, a2 + b2[2]);
    }
    if (lane == 0) {
        out[i*3+0] = xyz_in[i*3+0] + m0;
        out[i*3+1] = xyz_in[i*3+1] + m1;
        out[i*3+2] = xyz_in[i*3+2] + m2;
    }
}

// ---------------- folding MLP, fused upsample+noise in, xyz1 + packed pts out ------
__global__ __launch_bounds__(256) void fold_kernel(const float* __restrict__ pred_xyz,
                                                   const float* __restrict__ noise,
                                                   const float* __restrict__ featd,
                                                   const float* __restrict__ w1, const float* __restrict__ b1,
                                                   const float* __restrict__ w2, const float* __restrict__ b2,
                                                   const float* __restrict__ w3, const float* __restrict__ b3,
                                                   float* __restrict__ xyz1, float4* __restrict__ pts_out) {
    const int PTS = 16;
    int base = blockIdx.x * PTS;
    int tid = threadIdx.x;
    __shared__ __align__(16) float xin[PTS][100];
    __shared__ __align__(16) float h1[PTS][FOLDH];
    __shared__ __align__(16) float h2s[PTS][FOLDH];
    __shared__ float oxyz[PTS][3];
    for (int t = tid; t < PTS*100; t += 256) {
        int pt = t/100, k = t - pt*100;
        int gi = base + pt;
        float vv = 0.f;
        if (k < 3) {
            int b = gi >> 11, p = (gi & 2047) >> 2;
            vv = pred_xyz[(size_t)(b*PDIM + p)*3 + k] + 0.02f*noise[(size_t)gi*3 + k];
        } else if (k < 99) {
            int b = gi >> 11, p = (gi & 2047) >> 2;
            vv = featd[(size_t)(b*PDIM + p)*H2C + (k - 3)];
        }
        xin[pt][k] = vv;
    }
    __syncthreads();
    int c = tid;
    float acc[PTS];
    #pragma unroll
    for (int pt = 0; pt < PTS; ++pt) acc[pt] = b1[c];
    for (int k0 = 0; k0 < 96; k0 += 4) {
        float wa = w1[(k0+0)*FOLDH + c], wb = w1[(k0+1)*FOLDH + c];
        float wc = w1[(k0+2)*FOLDH + c], wd = w1[(k0+3)*FOLDH + c];
        #pragma unroll
        for (int pt = 0; pt < PTS; ++pt) {
            float4 xv = *(const float4*)&xin[pt][k0];
            acc[pt] += xv.x*wa + xv.y*wb + xv.z*wc + xv.w*wd;
        }
    }
    {
        float wa = w1[96*FOLDH + c], wb = w1[97*FOLDH + c], wc = w1[98*FOLDH + c];
        #pragma unroll
        for (int pt = 0; pt < PTS; ++pt) {
            float4 xv = *(const float4*)&xin[pt][96];
            acc[pt] += xv.x*wa + xv.y*wb + xv.z*wc;
        }
    }
    #pragma unroll
    for (int pt = 0; pt < PTS; ++pt) h1[pt][c] = frelu(acc[pt]);
    __syncthreads();
    #pragma unroll
    for (int pt = 0; pt < PTS; ++pt) acc[pt] = b2[c];
    for (int k0 = 0; k0 < FOLDH; k0 += 4) {
        float wa = w2[(k0+0)*FOLDH + c], wb = w2[(k0+1)*FOLDH + c];
        float wc = w2[(k0+2)*FOLDH + c], wd = w2[(k0+3)*FOLDH + c];
        #pragma unroll
        for (int pt = 0; pt < PTS; ++pt) {
            float4 hv = *(const float4*)&h1[pt][k0];
            acc[pt] += hv.x*wa + hv.y*wb + hv.z*wc + hv.w*wd;
        }
    }
    #pragma unroll
    for (int pt = 0; pt < PTS; ++pt) h2s[pt][c] = frelu(acc[pt]);
    __syncthreads();
    if (tid < PTS*3) {
        int pt = tid/3, cc = tid - pt*3;
        float a = b3[cc];
        for (int k0 = 0; k0 < FOLDH; k0 += 4) {
            float4 hv = *(const float4*)&h2s[pt][k0];
            a += hv.x*w3[(k0+0)*3+cc] + hv.y*w3[(k0+1)*3+cc] + hv.z*w3[(k0+2)*3+cc] + hv.w*w3[(k0+3)*3+cc];
        }
        int gi = base + pt;
        float res = xin[pt][cc] + a;
        xyz1[(size_t)gi*3 + cc] = res;
        oxyz[pt][cc] = res;
    }
    __syncthreads();
    if (tid < PTS) {
        float x = oxyz[tid][0], y = oxyz[tid][1], z = oxyz[tid][2];
        pts_out[base + tid] = make_float4(x, y, z, x*x + y*y + z*z);
    }
}

extern "C" void kernel_launch(void* const* d_in, const int* in_sizes, int n_in,
                              void* d_out, int out_size, void* d_ws, size_t ws_size,
                              hipStream_t stream) {
    const float* ctx_xyz    = (const float*)d_in[0];
    const float* ctx_tokens = (const float*)d_in[1];
    const float* pred_xyz   = (const float*)d_in[2];
    const float* noise      = (const float*)d_in[4];
    const float* c1w1 = (const float*)d_in[5];
    const float* c1b1 = (const float*)d_in[6];
    const float* c1w2 = (const float*)d_in[7];
    const float* c1b2 = (const float*)d_in[8];
    const float* c2w1 = (const float*)d_in[9];
    const float* c2b1 = (const float*)d_in[10];
    const float* c2w2 = (const float*)d_in[11];
    const float* c2b2 = (const float*)d_in[12];
    const float* cdw1 = (const float*)d_in[13];
    const float* cdb1 = (const float*)d_in[14];
    const float* cdw2 = (const float*)d_in[15];
    const float* cdb2 = (const float*)d_in[16];
    const float* fw1  = (const float*)d_in[17];
    const float* fb1  = (const float*)d_in[18];
    const float* fw2  = (const float*)d_in[19];
    const float* fb2  = (const float*)d_in[20];
    const float* fw3  = (const float*)d_in[21];
    const float* fb3  = (const float*)d_in[22];
    const float* rw1  = (const float*)d_in[23];
    const float* rb1  = (const float*)d_in[24];
    const float* rw2  = (const float*)d_in[25];
    const float* rb2  = (const float*)d_in[26];

    float* W = (float*)d_ws;
    // region A (aliased over time): dist (S1/S3/S4) -> pts (S6/S7) -> ur (S8)
    float* dist = W;                          // 2048*2048 = 4,194,304
    float4* pts = (float4*)W;                 // 8192 float4
    float* ur   = W;                          // 8192*384
    float* vr   = W + 3145728;                // ..6,291,456 (written S8; overlaps only dead bufs)
    // region T (transient, dead before vr written)
    float* u1    = W + 4194304;               // 2048*192
    float* v1    = u1 + N2*H1C;
    float* h_ctx = v1 + N2*H1C;
    float* h_tgt = h_ctx + N2*H1C;
    float* u2c   = h_tgt + N2*H1C;            // 2048*96 each
    float* v2c   = u2c + N2*H2C;
    float* u2t   = v2c + N2*H2C;
    float* v2t   = u2t + N2*H2C;              // ends 6,553,600
    // region P (persistent past vr)
    float* tfeat   = W + 6553600;             // 2048*96
    float* sqb     = tfeat + N2*H2C;
    float* sq_hctx = sqb + N2;
    float* sq_htgt = sq_hctx + N2;
    float* xyz1    = sq_htgt + N2;            // 8192*3
    int*   cidx1   = (int*)(xyz1 + N8*3);     // 2048*16
    int*   cidx2   = cidx1 + N2*16;           // 2048*8
    int*   tidx2   = cidx2 + N2*8;            // 2048*2
    int*   ridx    = tidx2 + N2*2;            // 8192*16 -> ends elem 6,965,248
    float* w2t1    = W + 6965248;             // 192*192 = 36,864
    float* w2t2    = w2t1 + 192*192;          // 96*96 = 9,216 -> ends 7,011,328
    float* distB   = W + 7011328;             // second dist buffer
    bool hasB = ws_size >= (size_t)(7011328 + 4194304) * 4;

    float* out_ctx = (float*)d_out;
    float* out_tgt = out_ctx + N2*3;

    dim3 b16(16, 16);
    const size_t ESM1 = (192 + 16*192 + 4 + 16 + 96 + 96) * sizeof(float);
    const size_t ESM2 = (96 + 8*96 + 4 + 8 + 96 + 96) * sizeof(float);
    const int NTRI = 32*33/2;   // 528 triangular tiles
    const float* NUL = nullptr;

    // --- prep: rowsq(tokens) + w2 transposes
    rowsq_kernel<<<N2/4, 256, 0, stream>>>(ctx_tokens, sqb, CDIM);
    wtrans_kernel<<<dim3(144, 2), 256, 0, stream>>>(c1w2, w2t1, c2w2, w2t2);

    // --- S1: dist(tokens) triangular; knn16 (tidx1 == first 4 of cidx1)
    dist64tri_kernel<<<NTRI, b16, 0, stream>>>(ctx_tokens, sqb, dist, N2, CDIM);
    knn_dist_rt_kernel<<<N2/4, 256, 0, stream>>>(dist, dist, N2, cidx1, cidx1, 16, 16, N2/4);

    // --- S2: u1/v1 GEMMs (z-paired), quad conv1 (col-per-thread, 192 thr)
    gemmquad_kernel<<<dim3(3, 32, 2), b16, 0, stream>>>(
        ctx_tokens, c1w1, c1w1 + 384*192, c1b1, u1,
        ctx_tokens, c1w1 + 384*192, NUL, NUL, v1,
        ctx_tokens, c1w1, NUL, NUL, u1,   // unused (z<2)
        ctx_tokens, c1w1, NUL, NUL, v1,
        H1C, CDIM);
    edge_quad1_kernel<<<dim3(N2, 2), 192, ESM1, stream>>>(u1, v1, w2t1, c1b2, cidx1,
                                                          h_ctx, sq_hctx, h_tgt, sq_htgt, N2);

    // --- S3/S4: dist(h_ctx)+dist(h_tgt) triangular, paired knn, u2/v2 quad, conv2
    if (hasB) {
        distpairtri_kernel<<<dim3(NTRI, 1, 2), b16, 0, stream>>>(h_ctx, sq_hctx, dist,
                                                                 h_tgt, sq_htgt, distB, N2, H1C);
        knn_dist_rt_kernel<<<2*(N2/4), 256, 0, stream>>>(dist, distB, N2, cidx2, tidx2, 8, 2, N2/4);
    } else {
        dist64tri_kernel<<<NTRI, b16, 0, stream>>>(h_ctx, sq_hctx, dist, N2, H1C);
        knn_dist_rt_kernel<<<N2/4, 256, 0, stream>>>(dist, dist, N2, cidx2, cidx2, 8, 8, N2/4);
        dist64tri_kernel<<<NTRI, b16, 0, stream>>>(h_tgt, sq_htgt, dist, N2, H1C);
        knn_dist_rt_kernel<<<N2/4, 256, 0, stream>>>(dist, dist, N2, tidx2, tidx2, 2, 2, N2/4);
    }
    gemmquad_kernel<<<dim3(2, 32, 4), b16, 0, stream>>>(
        h_ctx, c2w1, c2w1 + 192*96, c2b1, u2c,
        h_ctx, c2w1 + 192*96, NUL, NUL, v2c,
        h_tgt, c2w1, c2w1 + 192*96, c2b1, u2t,
        h_tgt, c2w1 + 192*96, NUL, NUL, v2t,
        H2C, H1C);
    edge_quad2_kernel<<<dim3(N2, 2), 128, ESM2, stream>>>(u2c, v2c, u2t, v2t, w2t2, c2b2,
                                                          cidx2, tidx2, cdw1, cdb1, cdw2, cdb2,
                                                          ctx_xyz, out_ctx, tfeat, N2);

    // --- S6: folding MLP (fused upsample+noise; emits xyz1 + packed pts)
    fold_kernel<<<N8/16, 256, 0, stream>>>(pred_xyz, noise, tfeat, fw1, fb1, fw2, fb2, fw3, fb3, xyz1, pts);

    // --- S7: refiner knn (8 rows/block, bitonic select)
    knn_xyz8_kernel<<<N8/8, 256, 0, stream>>>(pts, N8, ridx);

    // --- S8: refiner u/v gather-GEMMs (z-paired), residual EdgeConv to output
    gatherpair_kernel<<<dim3(6, N8/64, 2), b16, 0, stream>>>(
        tfeat, xyz1,
        rw1, rw1 + 99*384, rb1, ur,
        rw1 + 99*384, NUL, NUL, vr,
        384, 99);
    edge_ref_kernel<<<N8/4, 256, 0, stream>>>(ur, vr, rw2, rb2, ridx, xyz1, out_tgt, N8);
}

// Round 10
// 453.781 us; speedup vs baseline: 1.8013x; 1.1807x over previous
//
#include <hip/hip_runtime.h>

#define N2 2048      // B*P
#define N8 8192      // B*P*UP
#define CDIM 384
#define H1C 192      // C/2
#define H2C 96       // C/4
#define PDIM 512
#define KRR 16
#define FOLDH 256
#define XCAP 256
#define XTILE 1024
#define INFF 3.0e38f

__device__ __forceinline__ float frelu(float x) { return x > 0.f ? x : 0.f; }

// ---------------- 64-lane bitonic sorts (ascending) --------------------------------
__device__ __forceinline__ void bitonic64_val(float& d, int lane) {
    #pragma unroll
    for (int k = 2; k <= 64; k <<= 1) {
        #pragma unroll
        for (int j = k >> 1; j > 0; j >>= 1) {
            float od = __shfl_xor(d, j);
            bool lower = (lane & j) == 0;
            bool olt = od < d;
            bool take = lower ? olt : !olt;
            if (lane & k) take = !take;
            if (take) d = od;
        }
    }
}

__device__ __forceinline__ void bitonic64_pair(float& d, int& c, int lane) {
    #pragma unroll
    for (int k = 2; k <= 64; k <<= 1) {
        #pragma unroll
        for (int j = k >> 1; j > 0; j >>= 1) {
            float od = __shfl_xor(d, j);
            int   oc = __shfl_xor(c, j);
            bool lower = (lane & j) == 0;
            bool olt = (od < d) || (od == d && oc < c);
            bool take = lower ? olt : !olt;
            if (lane & k) take = !take;
            if (take) { d = od; c = oc; }
        }
    }
}

// ---------------- slow exact select fallback (cnt > 64, rare) ----------------------
__device__ __forceinline__ void select_slow(const float* bd, const int* bi, int cnt,
                                            int ksel, int row, int n, int* out, int lane) {
    float cd[4]; int cix[4];
    #pragma unroll
    for (int s = 0; s < 4; ++s) {
        int c = lane + 64*s;
        bool v = c < cnt;
        cd[s]  = v ? bd[c] : INFF;
        cix[s] = v ? bi[c] : 0x7fffffff;
    }
    for (int r = 0; r < ksel; ++r) {
        float lv = cd[0]; int li = cix[0];
        #pragma unroll
        for (int s = 1; s < 4; ++s) {
            if (cd[s] < lv || (cd[s] == lv && cix[s] < li)) { lv = cd[s]; li = cix[s]; }
        }
        float wv = lv; int wi = li;
        #pragma unroll
        for (int s = 1; s < 64; s <<= 1) {
            float ov = __shfl_xor(wv, s); int oi = __shfl_xor(wi, s);
            if (ov < wv || (ov == wv && oi < wi)) { wv = ov; wi = oi; }
        }
        if (lane == 0) {
            int safe = ((unsigned)wi < (unsigned)n) ? wi : ((row + 1) & (n - 1));
            out[row*ksel + r] = safe;
        }
        #pragma unroll
        for (int s = 0; s < 4; ++s) {
            if (cd[s] == wv && cix[s] == wi) { cd[s] = INFF; cix[s] = 0x7fffffff; }
        }
    }
}

// ---------------- row squared norms (wave per row) ---------------------------------
__global__ __launch_bounds__(256) void rowsq_kernel(const float* __restrict__ x,
                                                    float* __restrict__ sq, int d) {
    int wave = threadIdx.x >> 6, lane = threadIdx.x & 63;
    int row = blockIdx.x*4 + wave;
    float acc = 0.f;
    for (int k = lane; k < d; k += 64) { float v = x[(size_t)row*d + k]; acc += v*v; }
    #pragma unroll
    for (int s = 1; s < 64; s <<= 1) acc += __shfl_xor(acc, s);
    if (lane == 0) sq[row] = acc;
}

// ---------------- triangular symmetric dist: direct + mirrored tile ----------------
__device__ __forceinline__ void disttri_body(const float* __restrict__ x, const float* __restrict__ sq,
                                             float* __restrict__ dist, int n, int K) {
    int l = blockIdx.x;
    int by = (int)((sqrtf(8.f*(float)l + 1.f) - 1.f)*0.5f);
    while ((by+1)*(by+2)/2 <= l) ++by;
    while (by*(by+1)/2 > l) --by;
    int bx = l - by*(by+1)/2;
    int row0 = by*64, col0 = bx*64;
    __shared__ __align__(16) float As[16][68];
    __shared__ __align__(16) float Bs[16][68];
    __shared__ __align__(16) float T[64][68];
    int tx = threadIdx.x, ty = threadIdx.y;
    int t = ty*16 + tx;
    float acc[4][4] = {};
    for (int k0 = 0; k0 < K; k0 += 16) {
        #pragma unroll
        for (int r = 0; r < 4; ++r) {
            int e = t + 256*r; int kk = e & 15, mm = e >> 4;
            As[kk][mm] = x[(size_t)(row0+mm)*K + k0+kk];
            Bs[kk][mm] = x[(size_t)(col0+mm)*K + k0+kk];
        }
        __syncthreads();
        #pragma unroll
        for (int kk = 0; kk < 16; ++kk) {
            float4 a4 = *(const float4*)&As[kk][ty*4];
            float4 b4 = *(const float4*)&Bs[kk][tx*4];
            acc[0][0] += a4.x*b4.x; acc[0][1] += a4.x*b4.y; acc[0][2] += a4.x*b4.z; acc[0][3] += a4.x*b4.w;
            acc[1][0] += a4.y*b4.x; acc[1][1] += a4.y*b4.y; acc[1][2] += a4.y*b4.z; acc[1][3] += a4.y*b4.w;
            acc[2][0] += a4.z*b4.x; acc[2][1] += a4.z*b4.y; acc[2][2] += a4.z*b4.z; acc[2][3] += a4.z*b4.w;
            acc[3][0] += a4.w*b4.x; acc[3][1] += a4.w*b4.y; acc[3][2] += a4.w*b4.z; acc[3][3] += a4.w*b4.w;
        }
        __syncthreads();
    }
    bool mirror = (row0 != col0);
    #pragma unroll
    for (int i2 = 0; i2 < 4; ++i2) {
        int row = row0 + ty*4 + i2;
        float sr = sq[row];
        float4 o;
        o.x = sr + sq[col0+tx*4+0] - 2.f*acc[i2][0];
        o.y = sr + sq[col0+tx*4+1] - 2.f*acc[i2][1];
        o.z = sr + sq[col0+tx*4+2] - 2.f*acc[i2][2];
        o.w = sr + sq[col0+tx*4+3] - 2.f*acc[i2][3];
        *(float4*)&dist[(size_t)row*n + col0 + tx*4] = o;
        if (mirror) {
            T[tx*4+0][ty*4+i2] = o.x;
            T[tx*4+1][ty*4+i2] = o.y;
            T[tx*4+2][ty*4+i2] = o.z;
            T[tx*4+3][ty*4+i2] = o.w;
        }
    }
    if (mirror) {
        __syncthreads();
        #pragma unroll
        for (int i2 = 0; i2 < 4; ++i2) {
            int orow = col0 + ty*4 + i2;
            float4 o = *(const float4*)&T[ty*4+i2][tx*4];
            *(float4*)&dist[(size_t)orow*n + row0 + tx*4] = o;
        }
    }
}

__global__ __launch_bounds__(256) void dist64tri_kernel(const float* __restrict__ x,
                                                        const float* __restrict__ sq,
                                                        float* __restrict__ dist, int n, int K) {
    disttri_body(x, sq, dist, n, K);
}

__global__ __launch_bounds__(256) void distpairtri_kernel(const float* __restrict__ xA,
                                                          const float* __restrict__ sqA,
                                                          float* __restrict__ dA,
                                                          const float* __restrict__ xB,
                                                          const float* __restrict__ sqB,
                                                          float* __restrict__ dB, int n, int K) {
    const float* x  = blockIdx.z ? xB : xA;
    const float* sq = blockIdx.z ? sqB : sqA;
    float* dist     = blockIdx.z ? dB : dA;
    disttri_body(x, sq, dist, n, K);
}

// ---------------- shared 64x64 GEMM tile body: C = A @ (Bw - BwB) + bias -----------
__device__ __forceinline__ void gemm_body(const float* __restrict__ A, const float* __restrict__ Bw,
                                          const float* __restrict__ BwB, const float* __restrict__ bias,
                                          float* __restrict__ C, int m, int K) {
    __shared__ __align__(16) float As[16][68];
    __shared__ __align__(16) float Bs[16][68];
    int tx = threadIdx.x, ty = threadIdx.y;
    int t = ty*16 + tx;
    int row0 = blockIdx.y*64, col0 = blockIdx.x*64;
    float acc[4][4] = {};
    for (int k0 = 0; k0 < K; k0 += 16) {
        #pragma unroll
        for (int r = 0; r < 4; ++r) {
            int e = t + 256*r; int kk = e & 15, mm = e >> 4;
            As[kk][mm] = (k0 + kk < K) ? A[(size_t)(row0+mm)*K + k0+kk] : 0.f;
        }
        #pragma unroll
        for (int r = 0; r < 4; ++r) {
            int e = t + 256*r; int nn = e & 63, kk = e >> 6;
            int col = col0 + nn, k = k0 + kk;
            float bv = 0.f;
            if (k < K && col < m) {
                bv = Bw[(size_t)k*m + col];
                if (BwB) bv -= BwB[(size_t)k*m + col];
            }
            Bs[kk][nn] = bv;
        }
        __syncthreads();
        #pragma unroll
        for (int kk = 0; kk < 16; ++kk) {
            float4 a4 = *(const float4*)&As[kk][ty*4];
            float4 b4 = *(const float4*)&Bs[kk][tx*4];
            acc[0][0] += a4.x*b4.x; acc[0][1] += a4.x*b4.y; acc[0][2] += a4.x*b4.z; acc[0][3] += a4.x*b4.w;
            acc[1][0] += a4.y*b4.x; acc[1][1] += a4.y*b4.y; acc[1][2] += a4.y*b4.z; acc[1][3] += a4.y*b4.w;
            acc[2][0] += a4.z*b4.x; acc[2][1] += a4.z*b4.y; acc[2][2] += a4.z*b4.z; acc[2][3] += a4.z*b4.w;
            acc[3][0] += a4.w*b4.x; acc[3][1] += a4.w*b4.y; acc[3][2] += a4.w*b4.z; acc[3][3] += a4.w*b4.w;
        }
        __syncthreads();
    }
    #pragma unroll
    for (int i2 = 0; i2 < 4; ++i2) {
        int row = row0 + ty*4 + i2;
        #pragma unroll
        for (int j2 = 0; j2 < 4; ++j2) {
            int col = col0 + tx*4 + j2;
            if (col < m) C[(size_t)row*m + col] = acc[i2][j2] + (bias ? bias[col] : 0.f);
        }
    }
}

__global__ __launch_bounds__(256) void gemmquad_kernel(
    const float* A0, const float* Bw0, const float* BwB0, const float* bias0, float* C0,
    const float* A1, const float* Bw1, const float* BwB1, const float* bias1, float* C1,
    const float* A2, const float* Bw2, const float* BwB2, const float* bias2, float* C2,
    const float* A3, const float* Bw3, const float* BwB3, const float* bias3, float* C3,
    int m, int K) {
    int z = blockIdx.z;
    const float* A    = (z==0)?A0 :(z==1)?A1 :(z==2)?A2 :A3;
    const float* Bw   = (z==0)?Bw0:(z==1)?Bw1:(z==2)?Bw2:Bw3;
    const float* BwB  = (z==0)?BwB0:(z==1)?BwB1:(z==2)?BwB2:BwB3;
    const float* bias = (z==0)?bias0:(z==1)?bias1:(z==2)?bias2:bias3;
    float* C          = (z==0)?C0 :(z==1)?C1 :(z==2)?C2 :C3;
    gemm_body(A, Bw, BwB, bias, C, m, K);
}

// ---------------- EdgeConv layer-2 as gather-A GEMM --------------------------------
// S[(i*ETOT+e), h] = relu(u[i][h] + v[j(i,e)][h]);  O = S @ Bw + bias
template<int ETOT, int SELF, int IDXS, int YT>
__device__ __forceinline__ void edge_gemm_body(const float* __restrict__ u, const float* __restrict__ v,
                                               const int* __restrict__ idx,
                                               const float* __restrict__ Bw, const float* __restrict__ bias,
                                               float* __restrict__ O, int m, int K, int npts) {
    if ((int)blockIdx.y >= YT) return;
    __shared__ __align__(16) float As[16][68];
    __shared__ __align__(16) float Bs[16][68];
    int tx = threadIdx.x, ty = threadIdx.y;
    int t = ty*16 + tx;
    int row0 = blockIdx.y*64, col0 = blockIdx.x*64;
    float acc[4][4] = {};
    for (int k0 = 0; k0 < K; k0 += 16) {
        #pragma unroll
        for (int r = 0; r < 4; ++r) {
            int e_ = t + 256*r; int kk = e_ & 15, mm = e_ >> 4;
            int row = row0 + mm, k = k0 + kk;
            int i = row / ETOT;
            int e = row - i*ETOT;
            int j = (SELF && e == 0) ? i : idx[i*IDXS + (e - SELF)];
            j = ((unsigned)j < (unsigned)npts) ? j : i;
            As[kk][mm] = frelu(u[(size_t)i*K + k] + v[(size_t)j*K + k]);
        }
        #pragma unroll
        for (int r = 0; r < 4; ++r) {
            int e_ = t + 256*r; int nn = e_ & 63, kk = e_ >> 6;
            Bs[kk][nn] = Bw[(size_t)(k0+kk)*m + col0 + nn];
        }
        __syncthreads();
        #pragma unroll
        for (int kk = 0; kk < 16; ++kk) {
            float4 a4 = *(const float4*)&As[kk][ty*4];
            float4 b4 = *(const float4*)&Bs[kk][tx*4];
            acc[0][0] += a4.x*b4.x; acc[0][1] += a4.x*b4.y; acc[0][2] += a4.x*b4.z; acc[0][3] += a4.x*b4.w;
            acc[1][0] += a4.y*b4.x; acc[1][1] += a4.y*b4.y; acc[1][2] += a4.y*b4.z; acc[1][3] += a4.y*b4.w;
            acc[2][0] += a4.z*b4.x; acc[2][1] += a4.z*b4.y; acc[2][2] += a4.z*b4.z; acc[2][3] += a4.z*b4.w;
            acc[3][0] += a4.w*b4.x; acc[3][1] += a4.w*b4.y; acc[3][2] += a4.w*b4.z; acc[3][3] += a4.w*b4.w;
        }
        __syncthreads();
    }
    #pragma unroll
    for (int i2 = 0; i2 < 4; ++i2) {
        int row = row0 + ty*4 + i2;
        #pragma unroll
        for (int j2 = 0; j2 < 4; ++j2) {
            int col = col0 + tx*4 + j2;
            O[(size_t)row*m + col] = acc[i2][j2] + bias[col];
        }
    }
}

__global__ __launch_bounds__(256) void edge_gemm1_kernel(const float* u1, const float* v1,
                                                         const int* cidx1,
                                                         const float* Bw, const float* bias,
                                                         float* Octx, float* Otgt, int npts) {
    if (blockIdx.z == 0) edge_gemm_body<16,0,16,512>(u1, v1, cidx1, Bw, bias, Octx, H1C, H1C, npts);
    else                 edge_gemm_body<5,1,16,160>(u1, v1, cidx1, Bw, bias, Otgt, H1C, H1C, npts);
}

__global__ __launch_bounds__(256) void edge_gemm2_kernel(const float* u2c, const float* v2c,
                                                         const float* u2t, const float* v2t,
                                                         const int* cidx2, const int* tidx2,
                                                         const float* Bw, const float* bias,
                                                         float* Octx, float* Otgt, int npts) {
    if (blockIdx.z == 0) edge_gemm_body<8,0,8,256>(u2c, v2c, cidx2, Bw, bias, Octx, H2C, H2C, npts);
    else                 edge_gemm_body<3,1,2,96>(u2t, v2t, tidx2, Bw, bias, Otgt, H2C, H2C, npts);
}

// ---------------- conv1 max-reduce + row-sq (y=0 ctx E=16, y=1 tgt E=5) ------------
__global__ __launch_bounds__(192) void reduce1_kernel(const float* __restrict__ O1c,
                                                      const float* __restrict__ O1t,
                                                      float* __restrict__ h_ctx, float* __restrict__ sq_c,
                                                      float* __restrict__ h_tgt, float* __restrict__ sq_t) {
    int i = blockIdx.x, tid = threadIdx.x, wave = tid >> 6, lane = tid & 63;
    __shared__ float pm[3];
    const float* O = blockIdx.y ? O1t : O1c;
    float* h   = blockIdx.y ? h_tgt : h_ctx;
    float* sqo = blockIdx.y ? sq_t : sq_c;
    int E = blockIdx.y ? 5 : 16;
    const float* base = O + (size_t)i*E*H1C + tid;
    float best = base[0];
    for (int e = 1; e < E; ++e) best = fmaxf(best, base[(size_t)e*H1C]);
    h[(size_t)i*H1C + tid] = best;
    float part = best*best;
    #pragma unroll
    for (int s = 1; s < 64; s <<= 1) part += __shfl_xor(part, s);
    if (lane == 0) pm[wave] = part;
    __syncthreads();
    if (tid == 0) sqo[i] = pm[0] + pm[1] + pm[2];
}

// ---------------- conv2 max-reduce: y=0 ctx (E=8 + fused cdef), y=1 tgt (E=3) ------
__global__ __launch_bounds__(128) void reduce2_kernel(const float* __restrict__ O2c,
                                                      const float* __restrict__ O2t,
                                                      const float* __restrict__ cdw1, const float* __restrict__ cdb1,
                                                      const float* __restrict__ cdw2, const float* __restrict__ cdb2,
                                                      const float* __restrict__ ctx_xyz,
                                                      float* __restrict__ out_ctx, float* __restrict__ tfeat) {
    int i = blockIdx.x, tid = threadIdx.x, wave = tid >> 6, lane = tid & 63;
    __shared__ float sf_[96], st2_[96];
    if (blockIdx.y == 1) {
        if (tid < 96) {
            const float* base = O2t + (size_t)i*3*H2C + tid;
            float best = fmaxf(fmaxf(base[0], base[H2C]), base[2*H2C]);
            tfeat[(size_t)i*H2C + tid] = best;
        }
        return;
    }
    if (tid < 96) {
        const float* base = O2c + (size_t)i*8*H2C + tid;
        float best = base[0];
        #pragma unroll
        for (int e = 1; e < 8; ++e) best = fmaxf(best, base[(size_t)e*H2C]);
        sf_[tid] = best;
    }
    __syncthreads();
    if (tid < 96) {
        float a = cdb1[tid];
        for (int k = 0; k < 96; ++k) a += sf_[k]*cdw1[k*96 + tid];
        st2_[tid] = frelu(a);
    }
    __syncthreads();
    if (wave == 0) {
        float s0 = st2_[lane];
        float p0 = s0*cdw2[lane*3+0], p1 = s0*cdw2[lane*3+1], p2 = s0*cdw2[lane*3+2];
        if (lane < 32) {
            float s1 = st2_[lane+64];
            p0 += s1*cdw2[(lane+64)*3+0];
            p1 += s1*cdw2[(lane+64)*3+1];
            p2 += s1*cdw2[(lane+64)*3+2];
        }
        #pragma unroll
        for (int s = 1; s < 64; s <<= 1) {
            p0 += __shfl_xor(p0, s); p1 += __shfl_xor(p1, s); p2 += __shfl_xor(p2, s);
        }
        if (lane == 0) {
            out_ctx[i*3+0] = ctx_xyz[i*3+0] + 0.05f*(cdb2[0] + p0);
            out_ctx[i*3+1] = ctx_xyz[i*3+1] + 0.05f*(cdb2[1] + p1);
            out_ctx[i*3+2] = ctx_xyz[i*3+2] + 0.05f*(cdb2[2] + p2);
        }
    }
}

// refiner gather-GEMM pair: A row gathered from [featd(96) | xyzg(3)], K = 99
__global__ __launch_bounds__(256) void gatherpair_kernel(
    const float* __restrict__ featd, const float* __restrict__ xyzg,
    const float* Bw0, const float* BwB0, const float* bias0, float* C0,
    const float* Bw1, const float* BwB1, const float* bias1, float* C1,
    int m, int K) {
    int z = blockIdx.z;
    const float* Bw   = z ? Bw1 : Bw0;
    const float* BwB  = z ? BwB1 : BwB0;
    const float* bias = z ? bias1 : bias0;
    float* C          = z ? C1 : C0;
    __shared__ __align__(16) float As[16][68];
    __shared__ __align__(16) float Bs[16][68];
    int tx = threadIdx.x, ty = threadIdx.y;
    int t = ty*16 + tx;
    int row0 = blockIdx.y*64, col0 = blockIdx.x*64;
    float acc[4][4] = {};
    for (int k0 = 0; k0 < K; k0 += 16) {
        #pragma unroll
        for (int r = 0; r < 4; ++r) {
            int e = t + 256*r; int kk = e & 15, mm = e >> 4;
            int k = k0 + kk, grow = row0 + mm;
            float av = 0.f;
            if (k < K) {
                if (k < 96) { int b = grow >> 11, p = (grow & 2047) >> 2;
                              av = featd[(size_t)(b*PDIM + p)*H2C + k]; }
                else av = xyzg[(size_t)grow*3 + (k - 96)];
            }
            As[kk][mm] = av;
        }
        #pragma unroll
        for (int r = 0; r < 4; ++r) {
            int e = t + 256*r; int nn = e & 63, kk = e >> 6;
            int col = col0 + nn, k = k0 + kk;
            float bv = 0.f;
            if (k < K && col < m) {
                bv = Bw[(size_t)k*m + col];
                if (BwB) bv -= BwB[(size_t)k*m + col];
            }
            Bs[kk][nn] = bv;
        }
        __syncthreads();
        #pragma unroll
        for (int kk = 0; kk < 16; ++kk) {
            float4 a4 = *(const float4*)&As[kk][ty*4];
            float4 b4 = *(const float4*)&Bs[kk][tx*4];
            acc[0][0] += a4.x*b4.x; acc[0][1] += a4.x*b4.y; acc[0][2] += a4.x*b4.z; acc[0][3] += a4.x*b4.w;
            acc[1][0] += a4.y*b4.x; acc[1][1] += a4.y*b4.y; acc[1][2] += a4.y*b4.z; acc[1][3] += a4.y*b4.w;
            acc[2][0] += a4.z*b4.x; acc[2][1] += a4.z*b4.y; acc[2][2] += a4.z*b4.z; acc[2][3] += a4.z*b4.w;
            acc[3][0] += a4.w*b4.x; acc[3][1] += a4.w*b4.y; acc[3][2] += a4.w*b4.z; acc[3][3] += a4.w*b4.w;
        }
        __syncthreads();
    }
    #pragma unroll
    for (int i2 = 0; i2 < 4; ++i2) {
        int row = row0 + ty*4 + i2;
        #pragma unroll
        for (int j2 = 0; j2 < 4; ++j2) {
            int col = col0 + tx*4 + j2;
            if (col < m) C[(size_t)row*m + col] = acc[i2][j2] + (bias ? bias[col] : 0.f);
        }
    }
}

// ---------------- knn from dist rows (4 rows/block, bitonic select) ----------------
__global__ __launch_bounds__(256) void knn_dist_rt_kernel(const float* __restrict__ dA,
                                                          const float* __restrict__ dB, int n,
                                                          int* __restrict__ outA, int* __restrict__ outB,
                                                          int kA, int kB, int nblkA) {
    int wave = threadIdx.x >> 6, lane = threadIdx.x & 63;
    bool useB = (int)blockIdx.x >= nblkA;
    const float* dist = useB ? dB : dA;
    int* out = useB ? outB : outA;
    int ksel = useB ? kB : kA;
    int bx = useB ? (int)blockIdx.x - nblkA : (int)blockIdx.x;
    int row = bx*4 + wave;
    __shared__ float bufd[4][XCAP];
    __shared__ int   bufi[4][XCAP];
    __shared__ int   lcnt[4];
    const float4* drow = (const float4*)(dist + (size_t)row*n);
    int nq = n >> 2;
    float mv = INFF;
    for (int i = lane; i < nq; i += 64) {
        float4 d4 = drow[i]; int base = i*4;
        float a = (base+0 == row) ? INFF : d4.x;
        float b = (base+1 == row) ? INFF : d4.y;
        float c = (base+2 == row) ? INFF : d4.z;
        float d = (base+3 == row) ? INFF : d4.w;
        mv = fminf(mv, fminf(fminf(a,b), fminf(c,d)));
    }
    float sd = mv;
    bitonic64_val(sd, lane);
    float Tv = __shfl(sd, ksel - 1);
    if (lane == 0) lcnt[wave] = 0;
    for (int i = lane; i < nq; i += 64) {
        float4 d4 = drow[i]; int base = i*4;
        float dv4[4] = {d4.x, d4.y, d4.z, d4.w};
        #pragma unroll
        for (int q = 0; q < 4; ++q) {
            int col = base + q;
            if (col != row && dv4[q] <= Tv) {
                int pos = atomicAdd(&lcnt[wave], 1);
                if (pos < XCAP) { bufd[wave][pos] = dv4[q]; bufi[wave][pos] = col; }
            }
        }
    }
    int cnt = lcnt[wave]; if (cnt > XCAP) cnt = XCAP;
    if (cnt <= 64) {
        float d = (lane < cnt) ? bufd[wave][lane] : INFF;
        int   c = (lane < cnt) ? bufi[wave][lane] : 0x7fffffff;
        bitonic64_pair(d, c, lane);
        if (lane < ksel) {
            int safe = ((unsigned)c < (unsigned)n) ? c : ((row + 1) & (n - 1));
            out[row*ksel + lane] = safe;
        }
    } else {
        select_slow(bufd[wave], bufi[wave], cnt, ksel, row, n, out, lane);
    }
}

// ---------------- knn over packed xyz: 8 rows/block, 2 rows/wave -------------------
__global__ __launch_bounds__(256) void knn_xyz8_kernel(const float4* __restrict__ pts, int n,
                                                       int* __restrict__ out_idx) {
    int tid = threadIdx.x, wave = tid >> 6, lane = tid & 63;
    int rbase = blockIdx.x*8 + wave*2;
    __shared__ __align__(16) float4 tile[XTILE];
    __shared__ float bufd[8][XCAP];
    __shared__ int   bufi[8][XCAP];
    __shared__ int   lcnt[8];
    float4 P0 = pts[rbase], P1 = pts[rbase + 1];
    float mv0 = INFF, mv1 = INFF;
    for (int t0 = 0; t0 < n; t0 += XTILE) {
        __syncthreads();
        #pragma unroll
        for (int k = 0; k < XTILE/256; ++k) tile[tid + 256*k] = pts[t0 + tid + 256*k];
        __syncthreads();
        for (int c = lane; c < XTILE; c += 64) {
            float4 q = tile[c];
            int col = t0 + c;
            float d0 = P0.w + q.w - 2.f*(P0.x*q.x + P0.y*q.y + P0.z*q.z);
            float d1 = P1.w + q.w - 2.f*(P1.x*q.x + P1.y*q.y + P1.z*q.z);
            d0 = (col == rbase)     ? INFF : d0;
            d1 = (col == rbase + 1) ? INFF : d1;
            mv0 = fminf(mv0, d0);
            mv1 = fminf(mv1, d1);
        }
    }
    float s0 = mv0, s1 = mv1;
    bitonic64_val(s0, lane);
    bitonic64_val(s1, lane);
    float Tv0 = __shfl(s0, 15);
    float Tv1 = __shfl(s1, 15);
    if (lane < 2) lcnt[wave*2 + lane] = 0;
    for (int t0 = 0; t0 < n; t0 += XTILE) {
        __syncthreads();
        #pragma unroll
        for (int k = 0; k < XTILE/256; ++k) tile[tid + 256*k] = pts[t0 + tid + 256*k];
        __syncthreads();
        for (int c = lane; c < XTILE; c += 64) {
            float4 q = tile[c];
            int col = t0 + c;
            float d0 = P0.w + q.w - 2.f*(P0.x*q.x + P0.y*q.y + P0.z*q.z);
            float d1 = P1.w + q.w - 2.f*(P1.x*q.x + P1.y*q.y + P1.z*q.z);
            if (col != rbase && d0 <= Tv0) {
                int pos = atomicAdd(&lcnt[wave*2], 1);
                if (pos < XCAP) { bufd[wave*2][pos] = d0; bufi[wave*2][pos] = col; }
            }
            if (col != rbase + 1 && d1 <= Tv1) {
                int pos = atomicAdd(&lcnt[wave*2 + 1], 1);
                if (pos < XCAP) { bufd[wave*2 + 1][pos] = d1; bufi[wave*2 + 1][pos] = col; }
            }
        }
    }
    for (int jj = 0; jj < 2; ++jj) {
        int brow = wave*2 + jj, row = rbase + jj;
        int cnt = lcnt[brow]; if (cnt > XCAP) cnt = XCAP;
        if (cnt <= 64) {
            float d = (lane < cnt) ? bufd[brow][lane] : INFF;
            int   c = (lane < cnt) ? bufi[brow][lane] : 0x7fffffff;
            bitonic64_pair(d, c, lane);
            if (lane < 16) {
                int safe = ((unsigned)c < (unsigned)n) ? c : ((row + 1) & (n - 1));
                out_idx[row*16 + lane] = safe;
            }
        } else {
            select_slow(bufd[brow], bufi[brow], cnt, 16, row, n, out_idx, lane);
        }
    }
}

// ---------------- refiner EdgeConv (H1=384, H2=3), wave per point ------------------
__global__ __launch_bounds__(256) void edge_ref_kernel(const float* __restrict__ ur,
                                                       const float* __restrict__ vr,
                                                       const float* __restrict__ w2,
                                                       const float* __restrict__ b2,
                                                       const int* __restrict__ idx,
                                                       const float* __restrict__ xyz_in,
                                                       float* __restrict__ out, int n) {
    int wave = threadIdx.x >> 6, lane = threadIdx.x & 63;
    int i = blockIdx.x*4 + wave;
    if (i >= n) return;
    float m0 = -INFF, m1 = -INFF, m2 = -INFF;
    float uh[6];
    #pragma unroll
    for (int t = 0; t < 6; ++t) uh[t] = ur[(size_t)i*384 + lane + 64*t];
    for (int e = 0; e < KRR; ++e) {
        int j = idx[i*KRR + e];
        j = ((unsigned)j < (unsigned)n) ? j : i;
        float a0 = 0.f, a1 = 0.f, a2 = 0.f;
        #pragma unroll
        for (int t = 0; t < 6; ++t) {
            int h = lane + 64*t;
            float tv = frelu(uh[t] + vr[(size_t)j*384 + h]);
            a0 += tv*w2[h*3+0]; a1 += tv*w2[h*3+1]; a2 += tv*w2[h*3+2];
        }
        #pragma unroll
        for (int s = 32; s > 0; s >>= 1) {
            a0 += __shfl_xor(a0, s); a1 += __shfl_xor(a1, s); a2 += __shfl_xor(a2, s);
        }
        m0 = fmaxf(m0, a0 + b2[0]); m1 = fmaxf(m1, a1 + b2[1]); m2 = fmaxf(m2, a2 + b2[2]);
    }
    if (lane == 0) {
        out[i*3+0] = xyz_in[i*3+0] + m0;
        out[i*3+1] = xyz_in[i*3+1] + m1;
        out[i*3+2] = xyz_in[i*3+2] + m2;
    }
}

// ---------------- folding MLP, fused upsample+noise in, xyz1 + packed pts out ------
__global__ __launch_bounds__(256) void fold_kernel(const float* __restrict__ pred_xyz,
                                                   const float* __restrict__ noise,
                                                   const float* __restrict__ featd,
                                                   const float* __restrict__ w1, const float* __restrict__ b1,
                                                   const float* __restrict__ w2, const float* __restrict__ b2,
                                                   const float* __restrict__ w3, const float* __restrict__ b3,
                                                   float* __restrict__ xyz1, float4* __restrict__ pts_out) {
    const int PTS = 16;
    int base = blockIdx.x * PTS;
    int tid = threadIdx.x;
    __shared__ __align__(16) float xin[PTS][100];
    __shared__ __align__(16) float h1[PTS][FOLDH];
    __shared__ __align__(16) float h2s[PTS][FOLDH];
    __shared__ float oxyz[PTS][3];
    for (int t = tid; t < PTS*100; t += 256) {
        int pt = t/100, k = t - pt*100;
        int gi = base + pt;
        float vv = 0.f;
        if (k < 3) {
            int b = gi >> 11, p = (gi & 2047) >> 2;
            vv = pred_xyz[(size_t)(b*PDIM + p)*3 + k] + 0.02f*noise[(size_t)gi*3 + k];
        } else if (k < 99) {
            int b = gi >> 11, p = (gi & 2047) >> 2;
            vv = featd[(size_t)(b*PDIM + p)*H2C + (k - 3)];
        }
        xin[pt][k] = vv;
    }
    __syncthreads();
    int c = tid;
    float acc[PTS];
    #pragma unroll
    for (int pt = 0; pt < PTS; ++pt) acc[pt] = b1[c];
    for (int k0 = 0; k0 < 96; k0 += 4) {
        float wa = w1[(k0+0)*FOLDH + c], wb = w1[(k0+1)*FOLDH + c];
        float wc = w1[(k0+2)*FOLDH + c], wd = w1[(k0+3)*FOLDH + c];
        #pragma unroll
        for (int pt = 0; pt < PTS; ++pt) {
            float4 xv = *(const float4*)&xin[pt][k0];
            acc[pt] += xv.x*wa + xv.y*wb + xv.z*wc + xv.w*wd;
        }
    }
    {
        float wa = w1[96*FOLDH + c], wb = w1[97*FOLDH + c], wc = w1[98*FOLDH + c];
        #pragma unroll
        for (int pt = 0; pt < PTS; ++pt) {
            float4 xv = *(const float4*)&xin[pt][96];
            acc[pt] += xv.x*wa + xv.y*wb + xv.z*wc;
        }
    }
    #pragma unroll
    for (int pt = 0; pt < PTS; ++pt) h1[pt][c] = frelu(acc[pt]);
    __syncthreads();
    #pragma unroll
    for (int pt = 0; pt < PTS; ++pt) acc[pt] = b2[c];
    for (int k0 = 0; k0 < FOLDH; k0 += 4) {
        float wa = w2[(k0+0)*FOLDH + c], wb = w2[(k0+1)*FOLDH + c];
        float wc = w2[(k0+2)*FOLDH + c], wd = w2[(k0+3)*FOLDH + c];
        #pragma unroll
        for (int pt = 0; pt < PTS; ++pt) {
            float4 hv = *(const float4*)&h1[pt][k0];
            acc[pt] += hv.x*wa + hv.y*wb + hv.z*wc + hv.w*wd;
        }
    }
    #pragma unroll
    for (int pt = 0; pt < PTS; ++pt) h2s[pt][c] = frelu(acc[pt]);
    __syncthreads();
    if (tid < PTS*3) {
        int pt = tid/3, cc = tid - pt*3;
        float a = b3[cc];
        for (int k0 = 0; k0 < FOLDH; k0 += 4) {
            float4 hv = *(const float4*)&h2s[pt][k0];
            a += hv.x*w3[(k0+0)*3+cc] + hv.y*w3[(k0+1)*3+cc] + hv.z*w3[(k0+2)*3+cc] + hv.w*w3[(k0+3)*3+cc];
        }
        int gi = base + pt;
        float res = xin[pt][cc] + a;
        xyz1[(size_t)gi*3 + cc] = res;
        oxyz[pt][cc] = res;
    }
    __syncthreads();
    if (tid < PTS) {
        float x = oxyz[tid][0], y = oxyz[tid][1], z = oxyz[tid][2];
        pts_out[base + tid] = make_float4(x, y, z, x*x + y*y + z*z);
    }
}

extern "C" void kernel_launch(void* const* d_in, const int* in_sizes, int n_in,
                              void* d_out, int out_size, void* d_ws, size_t ws_size,
                              hipStream_t stream) {
    const float* ctx_xyz    = (const float*)d_in[0];
    const float* ctx_tokens = (const float*)d_in[1];
    const float* pred_xyz   = (const float*)d_in[2];
    const float* noise      = (const float*)d_in[4];
    const float* c1w1 = (const float*)d_in[5];
    const float* c1b1 = (const float*)d_in[6];
    const float* c1w2 = (const float*)d_in[7];
    const float* c1b2 = (const float*)d_in[8];
    const float* c2w1 = (const float*)d_in[9];
    const float* c2b1 = (const float*)d_in[10];
    const float* c2w2 = (const float*)d_in[11];
    const float* c2b2 = (const float*)d_in[12];
    const float* cdw1 = (const float*)d_in[13];
    const float* cdb1 = (const float*)d_in[14];
    const float* cdw2 = (const float*)d_in[15];
    const float* cdb2 = (const float*)d_in[16];
    const float* fw1  = (const float*)d_in[17];
    const float* fb1  = (const float*)d_in[18];
    const float* fw2  = (const float*)d_in[19];
    const float* fb2  = (const float*)d_in[20];
    const float* fw3  = (const float*)d_in[21];
    const float* fb3  = (const float*)d_in[22];
    const float* rw1  = (const float*)d_in[23];
    const float* rb1  = (const float*)d_in[24];
    const float* rw2  = (const float*)d_in[25];
    const float* rb2  = (const float*)d_in[26];

    float* W = (float*)d_ws;
    // Zone A (0 .. 8,388,608), staged aliasing over time:
    float* dist  = W;                   // S1/S3: 2048*2048
    float* distB = W + 4194304;         // S3: second dist (4.19M .. 8.39M)
    float* O1ctx = W;                   // S2: 32768*192 = 6,291,456
    float* O1tgt = W + 6291456;         // S2: 10240*192 = 1,966,080 (.. 8,257,536)
    float* O2ctx = W;                   // S4: 16384*96 = 1,572,864
    float* O2tgt = W + 1572864;         // S4: 6144*96 = 589,824
    float* ur    = W;                   // S8: 8192*384
    float* vr    = W + 3145728;         // S8
    // Persistent zone (8,388,608 ..):
    float* h_ctx = W + 8388608;         // 393,216
    float* h_tgt = h_ctx + 393216;
    float* UV    = h_tgt + 393216;      // 786,432 shared: [u1|v1] then [u2c|v2c|u2t|v2t]
    float* u1  = UV;            float* v1  = UV + 393216;
    float* u2c = UV;            float* v2c = UV + 196608;
    float* u2t = UV + 393216;   float* v2t = UV + 589824;
    float* tfeat = UV + 786432;         // 196,608
    float* xyz1  = tfeat + 196608;      // 24,576
    float4* pts  = (float4*)(xyz1 + 24576);   // 32,768 floats
    float* sqb     = (float*)pts + 32768;
    float* sq_hctx = sqb + N2;
    float* sq_htgt = sq_hctx + N2;
    int* cidx1 = (int*)(sq_htgt + N2);  // 2048*16
    int* cidx2 = cidx1 + N2*16;         // 2048*8
    int* tidx2 = cidx2 + N2*8;          // 2048*2
    int* ridx  = tidx2 + N2*2;          // 8192*16 -> total 10,405,888 floats = 41.6 MB

    float* out_ctx = (float*)d_out;
    float* out_tgt = out_ctx + N2*3;

    dim3 b16(16, 16);
    const int NTRI = 32*33/2;
    const float* NUL = nullptr;

    // --- S1: rowsq, dist(tokens), knn16 (tgt conv1 uses first 4 of cidx1)
    rowsq_kernel<<<N2/4, 256, 0, stream>>>(ctx_tokens, sqb, CDIM);
    dist64tri_kernel<<<NTRI, b16, 0, stream>>>(ctx_tokens, sqb, dist, N2, CDIM);
    knn_dist_rt_kernel<<<N2/4, 256, 0, stream>>>(dist, dist, N2, cidx1, cidx1, 16, 16, N2/4);

    // --- S2: u1/v1 GEMMs; conv1 as gather-GEMM pair; max-reduce (+row-sq)
    gemmquad_kernel<<<dim3(3, 32, 2), b16, 0, stream>>>(
        ctx_tokens, c1w1, c1w1 + 384*192, c1b1, u1,
        ctx_tokens, c1w1 + 384*192, NUL, NUL, v1,
        ctx_tokens, c1w1, NUL, NUL, u1,   // unused (z<2)
        ctx_tokens, c1w1, NUL, NUL, v1,
        H1C, CDIM);
    edge_gemm1_kernel<<<dim3(3, 512, 2), b16, 0, stream>>>(u1, v1, cidx1, c1w2, c1b2,
                                                           O1ctx, O1tgt, N2);
    reduce1_kernel<<<dim3(N2, 2), 192, 0, stream>>>(O1ctx, O1tgt, h_ctx, sq_hctx, h_tgt, sq_htgt);

    // --- S3: dist(h_ctx)+dist(h_tgt), paired knn, u2/v2 quad
    distpairtri_kernel<<<dim3(NTRI, 1, 2), b16, 0, stream>>>(h_ctx, sq_hctx, dist,
                                                             h_tgt, sq_htgt, distB, N2, H1C);
    knn_dist_rt_kernel<<<2*(N2/4), 256, 0, stream>>>(dist, distB, N2, cidx2, tidx2, 8, 2, N2/4);
    gemmquad_kernel<<<dim3(2, 32, 4), b16, 0, stream>>>(
        h_ctx, c2w1, c2w1 + 192*96, c2b1, u2c,
        h_ctx, c2w1 + 192*96, NUL, NUL, v2c,
        h_tgt, c2w1, c2w1 + 192*96, c2b1, u2t,
        h_tgt, c2w1 + 192*96, NUL, NUL, v2t,
        H2C, H1C);

    // --- S4: conv2 as gather-GEMM pair; max-reduce (ctx: fused cdef head)
    edge_gemm2_kernel<<<dim3(2, 256, 2), b16, 0, stream>>>(u2c, v2c, u2t, v2t, cidx2, tidx2,
                                                           c2w2, c2b2, O2ctx, O2tgt, N2);
    reduce2_kernel<<<dim3(N2, 2), 128, 0, stream>>>(O2ctx, O2tgt, cdw1, cdb1, cdw2, cdb2,
                                                    ctx_xyz, out_ctx, tfeat);

    // --- S6: folding MLP (fused upsample+noise; emits xyz1 + packed pts)
    fold_kernel<<<N8/16, 256, 0, stream>>>(pred_xyz, noise, tfeat, fw1, fb1, fw2, fb2, fw3, fb3, xyz1, pts);

    // --- S7: refiner knn
    knn_xyz8_kernel<<<N8/8, 256, 0, stream>>>(pts, N8, ridx);

    // --- S8: refiner u/v gather-GEMMs, residual EdgeConv to output
    gatherpair_kernel<<<dim3(6, N8/64, 2), b16, 0, stream>>>(
        tfeat, xyz1,
        rw1, rw1 + 99*384, rb1, ur,
        rw1 + 99*384, NUL, NUL, vr,
        384, 99);
    edge_ref_kernel<<<N8/4, 256, 0, stream>>>(ur, vr, rw2, rb2, ridx, xyz1, out_tgt, N8);
}